// Round 4
// baseline (2284.295 us; speedup 1.0000x reference)
//
#include <hip/hip_runtime.h>

#define N_NODES 50000
#define F_IN    1024
#define DD      64
#define PP      3
#define EE      1600000
#define NP      391         // partitions of 128 rows: (50000+127)/128
#define PCAP    4608        // slab capacity: mean 4096, sigma 64, +8 sigma

typedef __attribute__((ext_vector_type(8))) short short8v;   // 8 bf16 = 4 VGPR
typedef __attribute__((ext_vector_type(4))) float floatx4;

__device__ inline uint bf16_hi_trunc(float x) { return __float_as_uint(x) >> 16; }
__device__ inline float bf16tof(uint u) { return __uint_as_float(u << 16); }
__device__ inline uint bf16rne(float x) {
    uint b = __float_as_uint(x);
    return (b + 0x7fffu + ((b >> 16) & 1u)) >> 16;
}

// ---------------------------------------------------------------------------
// Split W0 [64,1024] and Wg [3,64,64] into bf16 hi/lo
// ---------------------------------------------------------------------------
__global__ __launch_bounds__(256) void split_weights(const float* __restrict__ W0,
                                                     const float* __restrict__ Wg,
                                                     ushort* __restrict__ W0h, ushort* __restrict__ W0l,
                                                     ushort* __restrict__ Wgh, ushort* __restrict__ Wgl)
{
    int i = blockIdx.x * 256 + threadIdx.x;
    if (i < 64 * 1024) {
        float x = W0[i];
        uint hb = bf16_hi_trunc(x);
        float r = x - bf16tof(hb);
        W0h[i] = (ushort)hb;
        W0l[i] = (ushort)bf16_hi_trunc(r);
    }
    int j = i - 64 * 1024;
    if (j >= 0 && j < PP * 64 * 64) {
        float x = Wg[j];
        uint hb = bf16_hi_trunc(x);
        float r = x - bf16tof(hb);
        Wgh[j] = (ushort)hb;
        Wgl[j] = (ushort)bf16_hi_trunc(r);
    }
}

// ---------------------------------------------------------------------------
// h = elu(feats @ W0^T + b0), bf16x3 MFMA (16x16x32), split done in-kernel.
// ---------------------------------------------------------------------------
__global__ __launch_bounds__(256) void gemm1_mfma(const float* __restrict__ feats,
                                                  const ushort* __restrict__ W0h,
                                                  const ushort* __restrict__ W0l,
                                                  const float* __restrict__ b0,
                                                  ushort* __restrict__ h_hi,
                                                  ushort* __restrict__ h_lo)
{
    __shared__ ushort Ah[64 * 64];
    __shared__ ushort Al[64 * 64];
    __shared__ ushort Bh[64 * 64];
    __shared__ ushort Bl[64 * 64];
    const int t = threadIdx.x;
    const int w = t >> 6, lane = t & 63;
    const int row0 = blockIdx.x * 64;
    const int l15 = lane & 15, l4 = lane >> 4;

    floatx4 acc[4] = {};

    for (int kc = 0; kc < 16; ++kc) {
        #pragma unroll
        for (int rep = 0; rep < 4; ++rep) {
            int idx = rep * 256 + t;             // 0..1023
            int r = idx >> 4, c4 = idx & 15;
            int gr = row0 + r; if (gr >= N_NODES) gr = N_NODES - 1;
            float4 v = *(const float4*)&feats[(size_t)gr * F_IN + kc * 64 + c4 * 4];
            uint h0 = bf16_hi_trunc(v.x), h1 = bf16_hi_trunc(v.y);
            uint h2 = bf16_hi_trunc(v.z), h3 = bf16_hi_trunc(v.w);
            uint l0 = bf16_hi_trunc(v.x - bf16tof(h0));
            uint l1 = bf16_hi_trunc(v.y - bf16tof(h1));
            uint l2 = bf16_hi_trunc(v.z - bf16tof(h2));
            uint l3 = bf16_hi_trunc(v.w - bf16tof(h3));
            int unit = (c4 >> 1) ^ (r & 7);
            int base = r * 64 + unit * 8 + (c4 & 1) * 4;
            *(uint2*)&Ah[base] = make_uint2(h0 | (h1 << 16), h2 | (h3 << 16));
            *(uint2*)&Al[base] = make_uint2(l0 | (l1 << 16), l2 | (l3 << 16));
        }
        #pragma unroll
        for (int rep = 0; rep < 2; ++rep) {
            int idx = rep * 256 + t;             // 0..511
            int c = idx >> 3, u8 = idx & 7;
            size_t g = (size_t)c * F_IN + kc * 64 + u8 * 8;
            uint4 vh = *(const uint4*)&W0h[g];
            uint4 vl = *(const uint4*)&W0l[g];
            int unit = u8 ^ (c & 7);
            *(uint4*)&Bh[c * 64 + unit * 8] = vh;
            *(uint4*)&Bl[c * 64 + unit * 8] = vl;
        }
        __syncthreads();
        #pragma unroll
        for (int ks = 0; ks < 2; ++ks) {
            int arow = w * 16 + l15;
            int au = (ks * 4 + l4) ^ (arow & 7);
            short8v ah = *(short8v*)&Ah[arow * 64 + au * 8];
            short8v al = *(short8v*)&Al[arow * 64 + au * 8];
            #pragma unroll
            for (int cf = 0; cf < 4; ++cf) {
                int bcol = cf * 16 + l15;
                int bu = (ks * 4 + l4) ^ (bcol & 7);
                short8v bh = *(short8v*)&Bh[bcol * 64 + bu * 8];
                short8v bl = *(short8v*)&Bl[bcol * 64 + bu * 8];
                acc[cf] = __builtin_amdgcn_mfma_f32_16x16x32_bf16(ah, bh, acc[cf], 0, 0, 0);
                acc[cf] = __builtin_amdgcn_mfma_f32_16x16x32_bf16(ah, bl, acc[cf], 0, 0, 0);
                acc[cf] = __builtin_amdgcn_mfma_f32_16x16x32_bf16(al, bh, acc[cf], 0, 0, 0);
            }
        }
        __syncthreads();
    }

    #pragma unroll
    for (int cf = 0; cf < 4; ++cf) {
        int col = cf * 16 + l15;
        #pragma unroll
        for (int r = 0; r < 4; ++r) {
            int gr = row0 + w * 16 + l4 * 4 + r;
            if (gr < N_NODES) {
                float x = acc[cf][r] + b0[col];
                x = x > 0.f ? x : (__expf(x) - 1.f);
                uint hb = bf16_hi_trunc(x);
                float rr = x - bf16tof(hb);
                h_hi[(size_t)gr * 64 + col] = (ushort)hb;
                h_lo[(size_t)gr * 64 + col] = (ushort)bf16_hi_trunc(rr);
            }
        }
    }
}

// ---------------------------------------------------------------------------
// s[p] = h @ Wg[p]^T  (bf16x3 MFMA, K=64 single chunk), output bf16.
// ---------------------------------------------------------------------------
__global__ __launch_bounds__(256) void gemm_s(const ushort* __restrict__ h_hi,
                                              const ushort* __restrict__ h_lo,
                                              const ushort* __restrict__ Wgh,
                                              const ushort* __restrict__ Wgl,
                                              ushort* __restrict__ s_all)
{
    __shared__ ushort Ah[64 * 64];
    __shared__ ushort Al[64 * 64];
    __shared__ ushort Bh[64 * 64];
    __shared__ ushort Bl[64 * 64];
    const int t = threadIdx.x;
    const int w = t >> 6, lane = t & 63;
    const int p = blockIdx.y;
    const int row0 = blockIdx.x * 64;
    const int l15 = lane & 15, l4 = lane >> 4;

    #pragma unroll
    for (int rep = 0; rep < 2; ++rep) {
        int idx = rep * 256 + t;
        int r = idx >> 3, u8 = idx & 7;
        int gr = row0 + r; if (gr >= N_NODES) gr = N_NODES - 1;
        size_t g = (size_t)gr * 64 + u8 * 8;
        int unit = u8 ^ (r & 7);
        *(uint4*)&Ah[r * 64 + unit * 8] = *(const uint4*)&h_hi[g];
        *(uint4*)&Al[r * 64 + unit * 8] = *(const uint4*)&h_lo[g];
        size_t gw = (size_t)p * 4096 + idx * 8;
        *(uint4*)&Bh[r * 64 + unit * 8] = *(const uint4*)&Wgh[gw];
        *(uint4*)&Bl[r * 64 + unit * 8] = *(const uint4*)&Wgl[gw];
    }
    __syncthreads();

    floatx4 acc[4] = {};
    #pragma unroll
    for (int ks = 0; ks < 2; ++ks) {
        int arow = w * 16 + l15;
        int au = (ks * 4 + l4) ^ (arow & 7);
        short8v ah = *(short8v*)&Ah[arow * 64 + au * 8];
        short8v al = *(short8v*)&Al[arow * 64 + au * 8];
        #pragma unroll
        for (int cf = 0; cf < 4; ++cf) {
            int bcol = cf * 16 + l15;
            int bu = (ks * 4 + l4) ^ (bcol & 7);
            short8v bh = *(short8v*)&Bh[bcol * 64 + bu * 8];
            short8v bl = *(short8v*)&Bl[bcol * 64 + bu * 8];
            acc[cf] = __builtin_amdgcn_mfma_f32_16x16x32_bf16(ah, bh, acc[cf], 0, 0, 0);
            acc[cf] = __builtin_amdgcn_mfma_f32_16x16x32_bf16(ah, bl, acc[cf], 0, 0, 0);
            acc[cf] = __builtin_amdgcn_mfma_f32_16x16x32_bf16(al, bh, acc[cf], 0, 0, 0);
        }
    }

    ushort* sp = s_all + (size_t)p * N_NODES * 64;
    #pragma unroll
    for (int cf = 0; cf < 4; ++cf) {
        int col = cf * 16 + l15;
        #pragma unroll
        for (int r = 0; r < 4; ++r) {
            int gr = row0 + w * 16 + l4 * 4 + r;
            if (gr < N_NODES)
                sp[(size_t)gr * 64 + col] = (ushort)bf16rne(acc[cf][r]);
        }
    }
}

// ---------------------------------------------------------------------------
// part1: partition edges into NP slabs of 128 rows each.
// Per block (2560 edges): LDS stage + histogram -> scan -> bulk reserve ->
// LDS counting-sort reorder -> coalesced flush of 8B entries.
// entry.x = col | (row_local<<16) | (p<<23); entry.y = fp32 val bits.
// ---------------------------------------------------------------------------
__global__ __launch_bounds__(256) void part1(const int*   __restrict__ rows,
                                             const int*   __restrict__ cols,
                                             const float* __restrict__ vals,
                                             int*  __restrict__ pcur,
                                             uint2* __restrict__ partbuf)
{
    __shared__ uint2 stage[2560];
    __shared__ uint2 sorted[2560];
    __shared__ int cnt[NP];
    __shared__ int scanb[512];
    __shared__ int curb[NP];
    __shared__ int gbase[NP];
    const int t = threadIdx.x;
    const size_t ebase = (size_t)blockIdx.x * 2560;

    for (int i = t; i < NP; i += 256) { cnt[i] = 0; curb[i] = 0; }
    __syncthreads();

    #pragma unroll
    for (int it = 0; it < 10; ++it) {
        int e = it * 256 + t;
        int r = rows[ebase + e];
        int c = cols[ebase + e];
        float v = vals[ebase + e];
        int p = r >> 7, rl = r & 127;
        stage[e] = make_uint2((uint)c | ((uint)rl << 16) | ((uint)p << 23),
                              __float_as_uint(v));
        atomicAdd(&cnt[p], 1);
    }
    __syncthreads();

    scanb[t]       = (t < NP) ? cnt[t] : 0;
    scanb[t + 256] = (t + 256 < NP) ? cnt[t + 256] : 0;
    __syncthreads();
    for (int off = 1; off < 512; off <<= 1) {
        int v0 = (t >= off) ? scanb[t - off] : 0;
        int v1 = (t + 256 >= off) ? scanb[t + 256 - off] : 0;
        __syncthreads();
        scanb[t] += v0; scanb[t + 256] += v1;
        __syncthreads();
    }
    // inclusive scan done; excl[p] = p ? scanb[p-1] : 0

    for (int p = t; p < NP; p += 256)
        gbase[p] = atomicAdd(&pcur[p], cnt[p]);
    __syncthreads();

    #pragma unroll
    for (int it = 0; it < 10; ++it) {
        uint2 e = stage[it * 256 + t];
        int p = e.x >> 23;
        int excl = p ? scanb[p - 1] : 0;
        int loc = excl + atomicAdd(&curb[p], 1);
        sorted[loc] = e;
    }
    __syncthreads();

    #pragma unroll
    for (int it = 0; it < 10; ++it) {
        int i = it * 256 + t;
        uint2 e = sorted[i];
        int p = e.x >> 23;
        int excl = p ? scanb[p - 1] : 0;
        int g = gbase[p] + (i - excl);
        if (g < PCAP) partbuf[(size_t)p * PCAP + g] = e;
    }
}

// ---------------------------------------------------------------------------
// part2: per-partition SpMM with LDS fp32 accumulation + fused bias/PReLU.
// Block = one partition (128 rows), 1024 threads = 16 waves; one edge per
// wave-iter: broadcast 8B meta, 64-lane bf16 s-row gather, ds_add_f32.
// ---------------------------------------------------------------------------
__global__ __launch_bounds__(1024) void part2(const uint2* __restrict__ partbuf,
                                              const int*   __restrict__ pcur,
                                              const ushort* __restrict__ s_p,
                                              const float* __restrict__ bgp,
                                              const float* __restrict__ alphap,
                                              float* __restrict__ outp)
{
    __shared__ float accum[128 * 64];
    const int t = threadIdx.x;
    const int p = blockIdx.x;
    const int lane = t & 63, w = t >> 6;   // 16 waves

    for (int i = t; i < 128 * 64; i += 1024) accum[i] = 0.f;
    __syncthreads();

    const int cnt = min(pcur[p], PCAP);
    const uint2* eb = partbuf + (size_t)p * PCAP;

    for (int e = w; e < cnt; e += 16) {
        uint2 pk = eb[e];
        uint col = pk.x & 0xffffu;
        uint rl  = (pk.x >> 16) & 0x7fu;
        float v  = __uint_as_float(pk.y);
        float sv = bf16tof((uint)s_p[(size_t)col * 64 + lane]);
        unsafeAtomicAdd(&accum[rl * 64 + lane], v * sv);
    }
    __syncthreads();

    const float al = alphap[0];
    const int r  = t >> 3;            // 0..127
    const int d0 = (t & 7) * 8;
    const int gr = p * 128 + r;
    if (gr < N_NODES) {
        const float* ap = &accum[r * 64 + d0];
        float o[8];
        #pragma unroll
        for (int j = 0; j < 8; ++j) {
            float x = ap[j] + bgp[d0 + j];
            o[j] = x > 0.f ? x : al * x;
        }
        *(float4*)&outp[(size_t)gr * 64 + d0]     = make_float4(o[0], o[1], o[2], o[3]);
        *(float4*)&outp[(size_t)gr * 64 + d0 + 4] = make_float4(o[4], o[5], o[6], o[7]);
    }
}

// ---------------------------------------------------------------------------
// Attention partial sums: sp[p] += column-sums of tanh(emb_p @ Wa^T + ba)
// ---------------------------------------------------------------------------
__global__ __launch_bounds__(256) void postproc(const float* __restrict__ emb,
                                                const float* __restrict__ Wa,
                                                const float* __restrict__ ba,
                                                float* __restrict__ sp)
{
    __shared__ float Ws[64][64];
    __shared__ float As[64][64];
    __shared__ float red[16][64];
    const int t  = threadIdx.x;
    const int tx = t & 15;
    const int ty = t >> 4;
    const int nb = (N_NODES + 63) >> 6;
    const int p  = blockIdx.x / nb;
    const int tb = blockIdx.x % nb;
    const int row0 = tb * 64;
    const float* embp = emb + (size_t)p * N_NODES * 64;

    #pragma unroll
    for (int rep = 0; rep < 4; ++rep) {
        int id = rep * 1024 + t * 4;
        int e  = id >> 6;
        int k4 = id & 63;
        float4 wv = *(const float4*)&Wa[id];
        Ws[k4+0][e] = wv.x; Ws[k4+1][e] = wv.y;
        Ws[k4+2][e] = wv.z; Ws[k4+3][e] = wv.w;
    }
    #pragma unroll
    for (int rep = 0; rep < 4; ++rep) {
        int id = rep * 1024 + t * 4;
        int m  = id >> 6;
        int d4 = id & 63;
        int gr = row0 + m;
        int gr2 = gr < N_NODES ? gr : N_NODES - 1;
        float4 xv = *(const float4*)&embp[(size_t)gr2 * 64 + d4];
        As[d4+0][m] = xv.x; As[d4+1][m] = xv.y;
        As[d4+2][m] = xv.z; As[d4+3][m] = xv.w;
    }
    __syncthreads();

    float acc[4][4] = {};
    #pragma unroll 8
    for (int kk = 0; kk < 64; ++kk) {
        float4 a4 = *(const float4*)&As[kk][ty * 4];
        float4 b4 = *(const float4*)&Ws[kk][tx * 4];
        float av[4] = {a4.x, a4.y, a4.z, a4.w};
        float bv[4] = {b4.x, b4.y, b4.z, b4.w};
        #pragma unroll
        for (int i = 0; i < 4; ++i)
            #pragma unroll
            for (int j = 0; j < 4; ++j)
                acc[i][j] += av[i] * bv[j];
    }

    float colsum[4] = {0.f, 0.f, 0.f, 0.f};
    #pragma unroll
    for (int i = 0; i < 4; ++i) {
        int gr = row0 + ty * 4 + i;
        if (gr < N_NODES) {
            #pragma unroll
            for (int j = 0; j < 4; ++j)
                colsum[j] += tanhf(acc[i][j] + ba[tx * 4 + j]);
        }
    }
    #pragma unroll
    for (int j = 0; j < 4; ++j) red[ty][tx * 4 + j] = colsum[j];
    __syncthreads();
    if (t < 64) {
        float ssum = 0.f;
        #pragma unroll
        for (int g = 0; g < 16; ++g) ssum += red[g][t];
        unsafeAtomicAdd(&sp[p * 64 + t], ssum);
    }
}

// ---------------------------------------------------------------------------
__global__ void beta_kernel(const float* __restrict__ sp,
                            const float* __restrict__ att,
                            float* __restrict__ beta)
{
    int lane = threadIdx.x;   // 64 threads
    float w[PP];
    #pragma unroll
    for (int p = 0; p < PP; ++p) {
        float x = sp[p * 64 + lane] * (1.0f / (float)N_NODES) * att[lane];
        #pragma unroll
        for (int off = 32; off; off >>= 1) x += __shfl_down(x, off);
        w[p] = __shfl(x, 0);
    }
    if (lane == 0) {
        float mx = fmaxf(w[0], fmaxf(w[1], w[2]));
        float e0 = __expf(w[0] - mx);
        float e1 = __expf(w[1] - mx);
        float e2 = __expf(w[2] - mx);
        float s = e0 + e1 + e2;
        beta[0] = e0 / s; beta[1] = e1 / s; beta[2] = e2 / s;
    }
}

// ---------------------------------------------------------------------------
__global__ __launch_bounds__(256) void combine(const float* __restrict__ emb,
                                               const float* __restrict__ beta,
                                               float* __restrict__ out)
{
    const float b0 = beta[0], b1 = beta[1], b2 = beta[2];
    const size_t tot = (size_t)N_NODES * 64;
    size_t i = ((size_t)blockIdx.x * 256 + threadIdx.x) * 4;
    if (i < tot) {
        float4 e0 = *(const float4*)&emb[i];
        float4 e1 = *(const float4*)&emb[tot + i];
        float4 e2 = *(const float4*)&emb[2 * tot + i];
        float4 o;
        o.x = b0 * e0.x + b1 * e1.x + b2 * e2.x;
        o.y = b0 * e0.y + b1 * e1.y + b2 * e2.y;
        o.z = b0 * e0.z + b1 * e1.z + b2 * e2.z;
        o.w = b0 * e0.w + b1 * e1.w + b2 * e2.w;
        *(float4*)&out[i] = o;
    }
}

// ---------------------------------------------------------------------------
extern "C" void kernel_launch(void* const* d_in, const int* in_sizes, int n_in,
                              void* d_out, int out_size, void* d_ws, size_t ws_size,
                              hipStream_t stream)
{
    const float* feats = (const float*)d_in[0];
    const int*   rows  = (const int*)  d_in[1];
    const int*   cols  = (const int*)  d_in[2];
    const float* vals  = (const float*)d_in[3];
    const float* W0    = (const float*)d_in[4];
    const float* b0    = (const float*)d_in[5];
    const float* Wg    = (const float*)d_in[6];
    const float* bg    = (const float*)d_in[7];
    const float* alpha = (const float*)d_in[8];
    const float* Wa    = (const float*)d_in[9];
    const float* ba    = (const float*)d_in[10];
    const float* att   = (const float*)d_in[11];
    float* out = (float*)d_out;

    const size_t ND = (size_t)N_NODES * 64;      // 3.2M elements
    char* base = (char*)d_ws;
    float*  emb    = (float*)base;               base += 3 * ND * 4;        // 38.4 MB
    ushort* h_hi   = (ushort*)base;              base += ND * 2;            // 6.4 MB
    ushort* h_lo   = (ushort*)base;              base += ND * 2;            // 6.4 MB
    ushort* s_all  = (ushort*)base;              base += 3 * ND * 2;        // 19.2 MB
    ushort* W0h    = (ushort*)base;              base += 64 * 1024 * 2;
    ushort* W0l    = (ushort*)base;              base += 64 * 1024 * 2;
    ushort* Wgh    = (ushort*)base;              base += PP * 64 * 64 * 2;
    ushort* Wgl    = (ushort*)base;              base += PP * 64 * 64 * 2;
    int*    pcur3  = (int*)base;                 base += PP * NP * 4;       // 4.7 KB
    float*  sp     = (float*)base;               base += 192 * 4;
    float*  beta   = (float*)base;               base += 64 * 4;
    base = (char*)(((size_t)base + 255) & ~(size_t)255);
    uint2*  partbuf = (uint2*)base;              base += (size_t)NP * PCAP * 8;  // 14.4 MB

    // zero pcur (3 paths) + sp partials in one shot (contiguous)
    hipMemsetAsync(pcur3, 0, (PP * NP + 192) * sizeof(int), stream);

    split_weights<<<(64 * 1024 + PP * 64 * 64 + 255) / 256, 256, 0, stream>>>(
        W0, Wg, W0h, W0l, Wgh, Wgl);

    gemm1_mfma<<<782, 256, 0, stream>>>(feats, W0h, W0l, b0, h_hi, h_lo);
    gemm_s<<<dim3(782, 3), 256, 0, stream>>>(h_hi, h_lo, Wgh, Wgl, s_all);

    for (int p = 0; p < PP; ++p) {
        part1<<<EE / 2560, 256, 0, stream>>>(rows + (size_t)p * EE,
                                             cols + (size_t)p * EE,
                                             vals + (size_t)p * EE,
                                             pcur3 + (size_t)p * NP, partbuf);
        part2<<<NP, 1024, 0, stream>>>(partbuf, pcur3 + (size_t)p * NP,
                                       s_all + (size_t)p * ND,
                                       bg + p * 64, alpha + p,
                                       emb + (size_t)p * ND);
    }

    postproc<<<3 * 782, 256, 0, stream>>>(emb, Wa, ba, sp);
    beta_kernel<<<1, 64, 0, stream>>>(sp, att, beta);
    combine<<<(int)(ND / 4 / 256), 256, 0, stream>>>(emb, beta, out);
}

// Round 5
// 439.650 us; speedup vs baseline: 5.1957x; 5.1957x over previous
//
#include <hip/hip_runtime.h>

#define N_NODES 50000
#define F_IN    1024
#define DD      64
#define PP      3
#define EE      1600000
#define NP      391         // partitions of 128 rows: (50000+127)/128
#define PCAP    4608        // slab capacity: mean 4096, sigma 64, +8 sigma

typedef __attribute__((ext_vector_type(8))) short short8v;   // 8 bf16 = 4 VGPR
typedef __attribute__((ext_vector_type(4))) float floatx4;

__device__ inline uint bf16_hi_trunc(float x) { return __float_as_uint(x) >> 16; }
__device__ inline float bf16tof(uint u) { return __uint_as_float(u << 16); }
__device__ inline uint bf16rne(float x) {
    uint b = __float_as_uint(x);
    return (b + 0x7fffu + ((b >> 16) & 1u)) >> 16;
}

// ---------------------------------------------------------------------------
// Split W0 [64,1024] and Wg [3,64,64] into bf16 hi/lo
// ---------------------------------------------------------------------------
__global__ __launch_bounds__(256) void split_weights(const float* __restrict__ W0,
                                                     const float* __restrict__ Wg,
                                                     ushort* __restrict__ W0h, ushort* __restrict__ W0l,
                                                     ushort* __restrict__ Wgh, ushort* __restrict__ Wgl)
{
    int i = blockIdx.x * 256 + threadIdx.x;
    if (i < 64 * 1024) {
        float x = W0[i];
        uint hb = bf16_hi_trunc(x);
        float r = x - bf16tof(hb);
        W0h[i] = (ushort)hb;
        W0l[i] = (ushort)bf16_hi_trunc(r);
    }
    int j = i - 64 * 1024;
    if (j >= 0 && j < PP * 64 * 64) {
        float x = Wg[j];
        uint hb = bf16_hi_trunc(x);
        float r = x - bf16tof(hb);
        Wgh[j] = (ushort)hb;
        Wgl[j] = (ushort)bf16_hi_trunc(r);
    }
}

// ---------------------------------------------------------------------------
// h = elu(feats @ W0^T + b0), bf16x3 MFMA (16x16x32), split done in-kernel.
// ---------------------------------------------------------------------------
__global__ __launch_bounds__(256) void gemm1_mfma(const float* __restrict__ feats,
                                                  const ushort* __restrict__ W0h,
                                                  const ushort* __restrict__ W0l,
                                                  const float* __restrict__ b0,
                                                  ushort* __restrict__ h_hi,
                                                  ushort* __restrict__ h_lo)
{
    __shared__ ushort Ah[64 * 64];
    __shared__ ushort Al[64 * 64];
    __shared__ ushort Bh[64 * 64];
    __shared__ ushort Bl[64 * 64];
    const int t = threadIdx.x;
    const int w = t >> 6, lane = t & 63;
    const int row0 = blockIdx.x * 64;
    const int l15 = lane & 15, l4 = lane >> 4;

    floatx4 acc[4] = {};

    for (int kc = 0; kc < 16; ++kc) {
        #pragma unroll
        for (int rep = 0; rep < 4; ++rep) {
            int idx = rep * 256 + t;             // 0..1023
            int r = idx >> 4, c4 = idx & 15;
            int gr = row0 + r; if (gr >= N_NODES) gr = N_NODES - 1;
            float4 v = *(const float4*)&feats[(size_t)gr * F_IN + kc * 64 + c4 * 4];
            uint h0 = bf16_hi_trunc(v.x), h1 = bf16_hi_trunc(v.y);
            uint h2 = bf16_hi_trunc(v.z), h3 = bf16_hi_trunc(v.w);
            uint l0 = bf16_hi_trunc(v.x - bf16tof(h0));
            uint l1 = bf16_hi_trunc(v.y - bf16tof(h1));
            uint l2 = bf16_hi_trunc(v.z - bf16tof(h2));
            uint l3 = bf16_hi_trunc(v.w - bf16tof(h3));
            int unit = (c4 >> 1) ^ (r & 7);
            int base = r * 64 + unit * 8 + (c4 & 1) * 4;
            *(uint2*)&Ah[base] = make_uint2(h0 | (h1 << 16), h2 | (h3 << 16));
            *(uint2*)&Al[base] = make_uint2(l0 | (l1 << 16), l2 | (l3 << 16));
        }
        #pragma unroll
        for (int rep = 0; rep < 2; ++rep) {
            int idx = rep * 256 + t;             // 0..511
            int c = idx >> 3, u8 = idx & 7;
            size_t g = (size_t)c * F_IN + kc * 64 + u8 * 8;
            uint4 vh = *(const uint4*)&W0h[g];
            uint4 vl = *(const uint4*)&W0l[g];
            int unit = u8 ^ (c & 7);
            *(uint4*)&Bh[c * 64 + unit * 8] = vh;
            *(uint4*)&Bl[c * 64 + unit * 8] = vl;
        }
        __syncthreads();
        #pragma unroll
        for (int ks = 0; ks < 2; ++ks) {
            int arow = w * 16 + l15;
            int au = (ks * 4 + l4) ^ (arow & 7);
            short8v ah = *(short8v*)&Ah[arow * 64 + au * 8];
            short8v al = *(short8v*)&Al[arow * 64 + au * 8];
            #pragma unroll
            for (int cf = 0; cf < 4; ++cf) {
                int bcol = cf * 16 + l15;
                int bu = (ks * 4 + l4) ^ (bcol & 7);
                short8v bh = *(short8v*)&Bh[bcol * 64 + bu * 8];
                short8v bl = *(short8v*)&Bl[bcol * 64 + bu * 8];
                acc[cf] = __builtin_amdgcn_mfma_f32_16x16x32_bf16(ah, bh, acc[cf], 0, 0, 0);
                acc[cf] = __builtin_amdgcn_mfma_f32_16x16x32_bf16(ah, bl, acc[cf], 0, 0, 0);
                acc[cf] = __builtin_amdgcn_mfma_f32_16x16x32_bf16(al, bh, acc[cf], 0, 0, 0);
            }
        }
        __syncthreads();
    }

    #pragma unroll
    for (int cf = 0; cf < 4; ++cf) {
        int col = cf * 16 + l15;
        #pragma unroll
        for (int r = 0; r < 4; ++r) {
            int gr = row0 + w * 16 + l4 * 4 + r;
            if (gr < N_NODES) {
                float x = acc[cf][r] + b0[col];
                x = x > 0.f ? x : (__expf(x) - 1.f);
                uint hb = bf16_hi_trunc(x);
                float rr = x - bf16tof(hb);
                h_hi[(size_t)gr * 64 + col] = (ushort)hb;
                h_lo[(size_t)gr * 64 + col] = (ushort)bf16_hi_trunc(rr);
            }
        }
    }
}

// ---------------------------------------------------------------------------
// s[p] = h @ Wg[p]^T  (bf16x3 MFMA, K=64 single chunk), output bf16.
// ---------------------------------------------------------------------------
__global__ __launch_bounds__(256) void gemm_s(const ushort* __restrict__ h_hi,
                                              const ushort* __restrict__ h_lo,
                                              const ushort* __restrict__ Wgh,
                                              const ushort* __restrict__ Wgl,
                                              ushort* __restrict__ s_all)
{
    __shared__ ushort Ah[64 * 64];
    __shared__ ushort Al[64 * 64];
    __shared__ ushort Bh[64 * 64];
    __shared__ ushort Bl[64 * 64];
    const int t = threadIdx.x;
    const int w = t >> 6, lane = t & 63;
    const int p = blockIdx.y;
    const int row0 = blockIdx.x * 64;
    const int l15 = lane & 15, l4 = lane >> 4;

    #pragma unroll
    for (int rep = 0; rep < 2; ++rep) {
        int idx = rep * 256 + t;
        int r = idx >> 3, u8 = idx & 7;
        int gr = row0 + r; if (gr >= N_NODES) gr = N_NODES - 1;
        size_t g = (size_t)gr * 64 + u8 * 8;
        int unit = u8 ^ (r & 7);
        *(uint4*)&Ah[r * 64 + unit * 8] = *(const uint4*)&h_hi[g];
        *(uint4*)&Al[r * 64 + unit * 8] = *(const uint4*)&h_lo[g];
        size_t gw = (size_t)p * 4096 + idx * 8;
        *(uint4*)&Bh[r * 64 + unit * 8] = *(const uint4*)&Wgh[gw];
        *(uint4*)&Bl[r * 64 + unit * 8] = *(const uint4*)&Wgl[gw];
    }
    __syncthreads();

    floatx4 acc[4] = {};
    #pragma unroll
    for (int ks = 0; ks < 2; ++ks) {
        int arow = w * 16 + l15;
        int au = (ks * 4 + l4) ^ (arow & 7);
        short8v ah = *(short8v*)&Ah[arow * 64 + au * 8];
        short8v al = *(short8v*)&Al[arow * 64 + au * 8];
        #pragma unroll
        for (int cf = 0; cf < 4; ++cf) {
            int bcol = cf * 16 + l15;
            int bu = (ks * 4 + l4) ^ (bcol & 7);
            short8v bh = *(short8v*)&Bh[bcol * 64 + bu * 8];
            short8v bl = *(short8v*)&Bl[bcol * 64 + bu * 8];
            acc[cf] = __builtin_amdgcn_mfma_f32_16x16x32_bf16(ah, bh, acc[cf], 0, 0, 0);
            acc[cf] = __builtin_amdgcn_mfma_f32_16x16x32_bf16(ah, bl, acc[cf], 0, 0, 0);
            acc[cf] = __builtin_amdgcn_mfma_f32_16x16x32_bf16(al, bh, acc[cf], 0, 0, 0);
        }
    }

    ushort* sp = s_all + (size_t)p * N_NODES * 64;
    #pragma unroll
    for (int cf = 0; cf < 4; ++cf) {
        int col = cf * 16 + l15;
        #pragma unroll
        for (int r = 0; r < 4; ++r) {
            int gr = row0 + w * 16 + l4 * 4 + r;
            if (gr < N_NODES)
                sp[(size_t)gr * 64 + col] = (ushort)bf16rne(acc[cf][r]);
        }
    }
}

// ---------------------------------------------------------------------------
// part1: partition edges into NP slabs of 128 rows each (validated in R4).
// entry.x = col | (row_local<<16) | (p<<23); entry.y = fp32 val bits.
// ---------------------------------------------------------------------------
__global__ __launch_bounds__(256) void part1(const int*   __restrict__ rows,
                                             const int*   __restrict__ cols,
                                             const float* __restrict__ vals,
                                             int*  __restrict__ pcur,
                                             uint2* __restrict__ partbuf)
{
    __shared__ uint2 stage[2560];
    __shared__ uint2 sorted[2560];
    __shared__ int cnt[NP];
    __shared__ int scanb[512];
    __shared__ int curb[NP];
    __shared__ int gbase[NP];
    const int t = threadIdx.x;
    const size_t ebase = (size_t)blockIdx.x * 2560;

    for (int i = t; i < NP; i += 256) { cnt[i] = 0; curb[i] = 0; }
    __syncthreads();

    #pragma unroll
    for (int it = 0; it < 10; ++it) {
        int e = it * 256 + t;
        int r = rows[ebase + e];
        int c = cols[ebase + e];
        float v = vals[ebase + e];
        int p = r >> 7, rl = r & 127;
        stage[e] = make_uint2((uint)c | ((uint)rl << 16) | ((uint)p << 23),
                              __float_as_uint(v));
        atomicAdd(&cnt[p], 1);
    }
    __syncthreads();

    scanb[t]       = (t < NP) ? cnt[t] : 0;
    scanb[t + 256] = (t + 256 < NP) ? cnt[t + 256] : 0;
    __syncthreads();
    for (int off = 1; off < 512; off <<= 1) {
        int v0 = (t >= off) ? scanb[t - off] : 0;
        int v1 = (t + 256 >= off) ? scanb[t + 256 - off] : 0;
        __syncthreads();
        scanb[t] += v0; scanb[t + 256] += v1;
        __syncthreads();
    }

    for (int p = t; p < NP; p += 256)
        gbase[p] = atomicAdd(&pcur[p], cnt[p]);
    __syncthreads();

    #pragma unroll
    for (int it = 0; it < 10; ++it) {
        uint2 e = stage[it * 256 + t];
        int p = e.x >> 23;
        int excl = p ? scanb[p - 1] : 0;
        int loc = excl + atomicAdd(&curb[p], 1);
        sorted[loc] = e;
    }
    __syncthreads();

    #pragma unroll
    for (int it = 0; it < 10; ++it) {
        int i = it * 256 + t;
        uint2 e = sorted[i];
        int p = e.x >> 23;
        int excl = p ? scanb[p - 1] : 0;
        int g = gbase[p] + (i - excl);
        if (g < PCAP) partbuf[(size_t)p * PCAP + g] = e;
    }
}

// ---------------------------------------------------------------------------
// sort_kernel: one block per partition. Counting-sort the slab by local row,
// write row-sorted slab + per-row [beg,end). Scattered writes are confined
// to this block's 37KB slab (single CU/XCD) -> full lines, no amplification.
// ---------------------------------------------------------------------------
__global__ __launch_bounds__(256) void sort_kernel(const uint2* __restrict__ partbuf,
                                                   const int*   __restrict__ pcur,
                                                   uint2* __restrict__ sortbuf,
                                                   int* __restrict__ rowbeg,
                                                   int* __restrict__ rowend)
{
    __shared__ uint2 stage[PCAP];     // 36.9 KB
    __shared__ int cnt[128];
    __shared__ int off[128];
    __shared__ int cur[128];
    const int t = threadIdx.x;
    const int p = blockIdx.x;
    const int n = min(pcur[p], PCAP);
    const uint2* src = partbuf + (size_t)p * PCAP;

    if (t < 128) cnt[t] = 0;
    __syncthreads();

    for (int i = t; i < n; i += 256) {
        uint2 e = src[i];
        stage[i] = e;
        atomicAdd(&cnt[(e.x >> 16) & 127], 1);
    }
    __syncthreads();

    if (t < 128) off[t] = cnt[t];
    __syncthreads();
    for (int o = 1; o < 128; o <<= 1) {
        int v = (t < 128 && t >= o) ? off[t - o] : 0;
        __syncthreads();
        if (t < 128 && t >= o) off[t] += v;
        __syncthreads();
    }
    if (t < 128) {
        int ex = off[t] - cnt[t];            // exclusive
        cur[t] = ex;
        int gr = p * 128 + t;
        if (gr < N_NODES) {
            rowbeg[gr] = p * PCAP + ex;
            rowend[gr] = p * PCAP + ex + cnt[t];
        }
    }
    __syncthreads();

    uint2* dst = sortbuf + (size_t)p * PCAP;
    for (int i = t; i < n; i += 256) {
        uint2 e = stage[i];
        int rl = (e.x >> 16) & 127;
        int pos = atomicAdd(&cur[rl], 1);
        dst[pos] = e;
    }
}

// ---------------------------------------------------------------------------
// Gather SpMM + bias + PReLU (R3-validated structure). One wave per row;
// lane = (slot<<4)|dq: 4 edges in flight, 16 dim-quads. 8B bf16 s gathers.
// ---------------------------------------------------------------------------
__global__ __launch_bounds__(256) void spmm_gather(const uint2*  __restrict__ epair,
                                                   const int*    __restrict__ rowbeg,
                                                   const int*    __restrict__ rowend,
                                                   const ushort* __restrict__ s_p,
                                                   const float*  __restrict__ bgp,
                                                   const float*  __restrict__ alphap,
                                                   float* __restrict__ outp)
{
    const int wid = (int)((blockIdx.x * 256 + threadIdx.x) >> 6);
    if (wid >= N_NODES) return;
    const int lane = threadIdx.x & 63;
    const int dq = lane & 15, slot = lane >> 4;
    const int e0 = rowbeg[wid], e1 = rowend[wid];

    float a0 = 0.f, a1 = 0.f, a2 = 0.f, a3 = 0.f;
    for (int e = e0; e < e1; e += 4) {
        int ee = e + slot;
        uint2 pk = (ee < e1) ? epair[ee] : make_uint2(0u, 0u);  // val=0 harmless
        float v  = __uint_as_float(pk.y);
        uint col = pk.x & 0xffffu;
        uint2 g = *(const uint2*)&s_p[(size_t)col * 64 + dq * 4];
        a0 += v * __uint_as_float(g.x << 16);
        a1 += v * __uint_as_float(g.x & 0xffff0000u);
        a2 += v * __uint_as_float(g.y << 16);
        a3 += v * __uint_as_float(g.y & 0xffff0000u);
    }
    a0 += __shfl_xor(a0, 16); a0 += __shfl_xor(a0, 32);
    a1 += __shfl_xor(a1, 16); a1 += __shfl_xor(a1, 32);
    a2 += __shfl_xor(a2, 16); a2 += __shfl_xor(a2, 32);
    a3 += __shfl_xor(a3, 16); a3 += __shfl_xor(a3, 32);

    if (slot == 0) {
        const float al = alphap[0];
        float4 o;
        o.x = a0 + bgp[dq * 4 + 0]; o.x = o.x > 0.f ? o.x : al * o.x;
        o.y = a1 + bgp[dq * 4 + 1]; o.y = o.y > 0.f ? o.y : al * o.y;
        o.z = a2 + bgp[dq * 4 + 2]; o.z = o.z > 0.f ? o.z : al * o.z;
        o.w = a3 + bgp[dq * 4 + 3]; o.w = o.w > 0.f ? o.w : al * o.w;
        *(float4*)&outp[(size_t)wid * 64 + dq * 4] = o;
    }
}

// ---------------------------------------------------------------------------
// Attention partial sums: sp[p] += column-sums of tanh(emb_p @ Wa^T + ba)
// ---------------------------------------------------------------------------
__global__ __launch_bounds__(256) void postproc(const float* __restrict__ emb,
                                                const float* __restrict__ Wa,
                                                const float* __restrict__ ba,
                                                float* __restrict__ sp)
{
    __shared__ float Ws[64][64];
    __shared__ float As[64][64];
    __shared__ float red[16][64];
    const int t  = threadIdx.x;
    const int tx = t & 15;
    const int ty = t >> 4;
    const int nb = (N_NODES + 63) >> 6;
    const int p  = blockIdx.x / nb;
    const int tb = blockIdx.x % nb;
    const int row0 = tb * 64;
    const float* embp = emb + (size_t)p * N_NODES * 64;

    #pragma unroll
    for (int rep = 0; rep < 4; ++rep) {
        int id = rep * 1024 + t * 4;
        int e  = id >> 6;
        int k4 = id & 63;
        float4 wv = *(const float4*)&Wa[id];
        Ws[k4+0][e] = wv.x; Ws[k4+1][e] = wv.y;
        Ws[k4+2][e] = wv.z; Ws[k4+3][e] = wv.w;
    }
    #pragma unroll
    for (int rep = 0; rep < 4; ++rep) {
        int id = rep * 1024 + t * 4;
        int m  = id >> 6;
        int d4 = id & 63;
        int gr = row0 + m;
        int gr2 = gr < N_NODES ? gr : N_NODES - 1;
        float4 xv = *(const float4*)&embp[(size_t)gr2 * 64 + d4];
        As[d4+0][m] = xv.x; As[d4+1][m] = xv.y;
        As[d4+2][m] = xv.z; As[d4+3][m] = xv.w;
    }
    __syncthreads();

    float acc[4][4] = {};
    #pragma unroll 8
    for (int kk = 0; kk < 64; ++kk) {
        float4 a4 = *(const float4*)&As[kk][ty * 4];
        float4 b4 = *(const float4*)&Ws[kk][tx * 4];
        float av[4] = {a4.x, a4.y, a4.z, a4.w};
        float bv[4] = {b4.x, b4.y, b4.z, b4.w};
        #pragma unroll
        for (int i = 0; i < 4; ++i)
            #pragma unroll
            for (int j = 0; j < 4; ++j)
                acc[i][j] += av[i] * bv[j];
    }

    float colsum[4] = {0.f, 0.f, 0.f, 0.f};
    #pragma unroll
    for (int i = 0; i < 4; ++i) {
        int gr = row0 + ty * 4 + i;
        if (gr < N_NODES) {
            #pragma unroll
            for (int j = 0; j < 4; ++j)
                colsum[j] += tanhf(acc[i][j] + ba[tx * 4 + j]);
        }
    }
    #pragma unroll
    for (int j = 0; j < 4; ++j) red[ty][tx * 4 + j] = colsum[j];
    __syncthreads();
    if (t < 64) {
        float ssum = 0.f;
        #pragma unroll
        for (int g = 0; g < 16; ++g) ssum += red[g][t];
        unsafeAtomicAdd(&sp[p * 64 + t], ssum);
    }
}

// ---------------------------------------------------------------------------
__global__ void beta_kernel(const float* __restrict__ sp,
                            const float* __restrict__ att,
                            float* __restrict__ beta)
{
    int lane = threadIdx.x;   // 64 threads
    float w[PP];
    #pragma unroll
    for (int p = 0; p < PP; ++p) {
        float x = sp[p * 64 + lane] * (1.0f / (float)N_NODES) * att[lane];
        #pragma unroll
        for (int off = 32; off; off >>= 1) x += __shfl_down(x, off);
        w[p] = __shfl(x, 0);
    }
    if (lane == 0) {
        float mx = fmaxf(w[0], fmaxf(w[1], w[2]));
        float e0 = __expf(w[0] - mx);
        float e1 = __expf(w[1] - mx);
        float e2 = __expf(w[2] - mx);
        float s = e0 + e1 + e2;
        beta[0] = e0 / s; beta[1] = e1 / s; beta[2] = e2 / s;
    }
}

// ---------------------------------------------------------------------------
__global__ __launch_bounds__(256) void combine(const float* __restrict__ emb,
                                               const float* __restrict__ beta,
                                               float* __restrict__ out)
{
    const float b0 = beta[0], b1 = beta[1], b2 = beta[2];
    const size_t tot = (size_t)N_NODES * 64;
    size_t i = ((size_t)blockIdx.x * 256 + threadIdx.x) * 4;
    if (i < tot) {
        float4 e0 = *(const float4*)&emb[i];
        float4 e1 = *(const float4*)&emb[tot + i];
        float4 e2 = *(const float4*)&emb[2 * tot + i];
        float4 o;
        o.x = b0 * e0.x + b1 * e1.x + b2 * e2.x;
        o.y = b0 * e0.y + b1 * e1.y + b2 * e2.y;
        o.z = b0 * e0.z + b1 * e1.z + b2 * e2.z;
        o.w = b0 * e0.w + b1 * e1.w + b2 * e2.w;
        *(float4*)&out[i] = o;
    }
}

// ---------------------------------------------------------------------------
extern "C" void kernel_launch(void* const* d_in, const int* in_sizes, int n_in,
                              void* d_out, int out_size, void* d_ws, size_t ws_size,
                              hipStream_t stream)
{
    const float* feats = (const float*)d_in[0];
    const int*   rows  = (const int*)  d_in[1];
    const int*   cols  = (const int*)  d_in[2];
    const float* vals  = (const float*)d_in[3];
    const float* W0    = (const float*)d_in[4];
    const float* b0    = (const float*)d_in[5];
    const float* Wg    = (const float*)d_in[6];
    const float* bg    = (const float*)d_in[7];
    const float* alpha = (const float*)d_in[8];
    const float* Wa    = (const float*)d_in[9];
    const float* ba    = (const float*)d_in[10];
    const float* att   = (const float*)d_in[11];
    float* out = (float*)d_out;

    const size_t ND = (size_t)N_NODES * 64;      // 3.2M elements
    char* base = (char*)d_ws;
    float*  emb    = (float*)base;               base += 3 * ND * 4;        // 38.4 MB
    ushort* h_hi   = (ushort*)base;              base += ND * 2;            // 6.4 MB
    ushort* h_lo   = (ushort*)base;              base += ND * 2;            // 6.4 MB
    ushort* s_all  = (ushort*)base;              base += 3 * ND * 2;        // 19.2 MB
    ushort* W0h    = (ushort*)base;              base += 64 * 1024 * 2;
    ushort* W0l    = (ushort*)base;              base += 64 * 1024 * 2;
    ushort* Wgh    = (ushort*)base;              base += PP * 64 * 64 * 2;
    ushort* Wgl    = (ushort*)base;              base += PP * 64 * 64 * 2;
    int*    pcur3  = (int*)base;                 base += PP * NP * 4;       // 4.7 KB
    float*  sp     = (float*)base;               base += 192 * 4;
    float*  beta   = (float*)base;               base += 64 * 4;
    int*    rowbeg = (int*)base;                 base += N_NODES * 4;       // 200 KB
    int*    rowend = (int*)base;                 base += N_NODES * 4;       // 200 KB
    base = (char*)(((size_t)base + 255) & ~(size_t)255);
    uint2*  partbuf = (uint2*)base;              base += (size_t)NP * PCAP * 8;  // 14.4 MB
    uint2*  sortbuf = (uint2*)base;              base += (size_t)NP * PCAP * 8;  // 14.4 MB

    // zero pcur (3 paths) + sp partials in one shot (contiguous)
    hipMemsetAsync(pcur3, 0, (PP * NP + 192) * sizeof(int), stream);

    split_weights<<<(64 * 1024 + PP * 64 * 64 + 255) / 256, 256, 0, stream>>>(
        W0, Wg, W0h, W0l, Wgh, Wgl);

    gemm1_mfma<<<782, 256, 0, stream>>>(feats, W0h, W0l, b0, h_hi, h_lo);
    gemm_s<<<dim3(782, 3), 256, 0, stream>>>(h_hi, h_lo, Wgh, Wgl, s_all);

    for (int p = 0; p < PP; ++p) {
        part1<<<EE / 2560, 256, 0, stream>>>(rows + (size_t)p * EE,
                                             cols + (size_t)p * EE,
                                             vals + (size_t)p * EE,
                                             pcur3 + (size_t)p * NP, partbuf);
        sort_kernel<<<NP, 256, 0, stream>>>(partbuf, pcur3 + (size_t)p * NP,
                                            sortbuf, rowbeg, rowend);
        spmm_gather<<<(N_NODES + 3) / 4, 256, 0, stream>>>(
            sortbuf, rowbeg, rowend, s_all + (size_t)p * ND,
            bg + p * 64, alpha + p, emb + (size_t)p * ND);
    }

    postproc<<<3 * 782, 256, 0, stream>>>(emb, Wa, ba, sp);
    beta_kernel<<<1, 64, 0, stream>>>(sp, att, beta);
    combine<<<(int)(ND / 4 / 256), 256, 0, stream>>>(emb, beta, out);
}

// Round 6
// 392.254 us; speedup vs baseline: 5.8235x; 1.1208x over previous
//
#include <hip/hip_runtime.h>

#define N_NODES 50000
#define F_IN    1024
#define DD      64
#define PP      3
#define EE      1600000
#define NPC     98          // coarse partitions of 512 rows: (50000+511)/512
#define CCAP    17664       // slab capacity: mean 16384, sigma 128, +10 sigma

typedef __attribute__((ext_vector_type(8))) short short8v;   // 8 bf16 = 4 VGPR
typedef __attribute__((ext_vector_type(4))) float floatx4;

__device__ inline float bf16tof(uint u) { return __uint_as_float(u << 16); }
__device__ inline uint bf16rne(float x) {
    uint b = __float_as_uint(x);
    return (b + 0x7fffu + ((b >> 16) & 1u)) >> 16;
}

// ---------------------------------------------------------------------------
// Round W0 [64,1024] and Wg [3,64,64] to single bf16
// ---------------------------------------------------------------------------
__global__ __launch_bounds__(256) void split_weights(const float* __restrict__ W0,
                                                     const float* __restrict__ Wg,
                                                     ushort* __restrict__ W0h,
                                                     ushort* __restrict__ Wgh)
{
    int i = blockIdx.x * 256 + threadIdx.x;
    if (i < 64 * 1024) W0h[i] = (ushort)bf16rne(W0[i]);
    int j = i - 64 * 1024;
    if (j >= 0 && j < PP * 64 * 64) Wgh[j] = (ushort)bf16rne(Wg[j]);
}

// ---------------------------------------------------------------------------
// h = elu(feats @ W0^T + b0), single-bf16 MFMA 16x16x32.
// Tile 64x64, BK=64, XOR-swizzled bf16 LDS (conflict-free ds_read_b128).
// ---------------------------------------------------------------------------
__global__ __launch_bounds__(256) void gemm1_mfma(const float* __restrict__ feats,
                                                  const ushort* __restrict__ W0h,
                                                  const float* __restrict__ b0,
                                                  ushort* __restrict__ h_bf)
{
    __shared__ ushort Ah[64 * 64];   // 8 KB
    __shared__ ushort Bh[64 * 64];
    const int t = threadIdx.x;
    const int w = t >> 6, lane = t & 63;
    const int row0 = blockIdx.x * 64;
    const int l15 = lane & 15, l4 = lane >> 4;

    floatx4 acc[4] = {};

    for (int kc = 0; kc < 16; ++kc) {
        #pragma unroll
        for (int rep = 0; rep < 4; ++rep) {
            int idx = rep * 256 + t;             // 0..1023
            int r = idx >> 4, c4 = idx & 15;
            int gr = row0 + r; if (gr >= N_NODES) gr = N_NODES - 1;
            float4 v = *(const float4*)&feats[(size_t)gr * F_IN + kc * 64 + c4 * 4];
            uint h0 = bf16rne(v.x), h1 = bf16rne(v.y);
            uint h2 = bf16rne(v.z), h3 = bf16rne(v.w);
            int unit = (c4 >> 1) ^ (r & 7);
            int base = r * 64 + unit * 8 + (c4 & 1) * 4;
            *(uint2*)&Ah[base] = make_uint2(h0 | (h1 << 16), h2 | (h3 << 16));
        }
        #pragma unroll
        for (int rep = 0; rep < 2; ++rep) {
            int idx = rep * 256 + t;             // 0..511
            int c = idx >> 3, u8 = idx & 7;
            uint4 vh = *(const uint4*)&W0h[(size_t)c * F_IN + kc * 64 + u8 * 8];
            int unit = u8 ^ (c & 7);
            *(uint4*)&Bh[c * 64 + unit * 8] = vh;
        }
        __syncthreads();
        #pragma unroll
        for (int ks = 0; ks < 2; ++ks) {
            int arow = w * 16 + l15;
            int au = (ks * 4 + l4) ^ (arow & 7);
            short8v ah = *(short8v*)&Ah[arow * 64 + au * 8];
            #pragma unroll
            for (int cf = 0; cf < 4; ++cf) {
                int bcol = cf * 16 + l15;
                int bu = (ks * 4 + l4) ^ (bcol & 7);
                short8v bh = *(short8v*)&Bh[bcol * 64 + bu * 8];
                acc[cf] = __builtin_amdgcn_mfma_f32_16x16x32_bf16(ah, bh, acc[cf], 0, 0, 0);
            }
        }
        __syncthreads();
    }

    #pragma unroll
    for (int cf = 0; cf < 4; ++cf) {
        int col = cf * 16 + l15;
        #pragma unroll
        for (int r = 0; r < 4; ++r) {
            int gr = row0 + w * 16 + l4 * 4 + r;
            if (gr < N_NODES) {
                float x = acc[cf][r] + b0[col];
                x = x > 0.f ? x : (__expf(x) - 1.f);
                h_bf[(size_t)gr * 64 + col] = (ushort)bf16rne(x);
            }
        }
    }
}

// ---------------------------------------------------------------------------
// s[p] = h @ Wg[p]^T  (single-bf16 MFMA, K=64), output bf16. grid (782,3)
// ---------------------------------------------------------------------------
__global__ __launch_bounds__(256) void gemm_s(const ushort* __restrict__ h_bf,
                                              const ushort* __restrict__ Wgh,
                                              ushort* __restrict__ s_all)
{
    __shared__ ushort Ah[64 * 64];
    __shared__ ushort Bh[64 * 64];
    const int t = threadIdx.x;
    const int w = t >> 6, lane = t & 63;
    const int p = blockIdx.y;
    const int row0 = blockIdx.x * 64;
    const int l15 = lane & 15, l4 = lane >> 4;

    #pragma unroll
    for (int rep = 0; rep < 2; ++rep) {
        int idx = rep * 256 + t;                 // 0..511
        int r = idx >> 3, u8 = idx & 7;
        int gr = row0 + r; if (gr >= N_NODES) gr = N_NODES - 1;
        int unit = u8 ^ (r & 7);
        *(uint4*)&Ah[r * 64 + unit * 8] = *(const uint4*)&h_bf[(size_t)gr * 64 + u8 * 8];
        *(uint4*)&Bh[r * 64 + unit * 8] = *(const uint4*)&Wgh[(size_t)p * 4096 + idx * 8];
    }
    __syncthreads();

    floatx4 acc[4] = {};
    #pragma unroll
    for (int ks = 0; ks < 2; ++ks) {
        int arow = w * 16 + l15;
        int au = (ks * 4 + l4) ^ (arow & 7);
        short8v ah = *(short8v*)&Ah[arow * 64 + au * 8];
        #pragma unroll
        for (int cf = 0; cf < 4; ++cf) {
            int bcol = cf * 16 + l15;
            int bu = (ks * 4 + l4) ^ (bcol & 7);
            short8v bh = *(short8v*)&Bh[bcol * 64 + bu * 8];
            acc[cf] = __builtin_amdgcn_mfma_f32_16x16x32_bf16(ah, bh, acc[cf], 0, 0, 0);
        }
    }

    ushort* sp = s_all + (size_t)p * N_NODES * 64;
    #pragma unroll
    for (int cf = 0; cf < 4; ++cf) {
        int col = cf * 16 + l15;
        #pragma unroll
        for (int r = 0; r < 4; ++r) {
            int gr = row0 + w * 16 + l4 * 4 + r;
            if (gr < N_NODES)
                sp[(size_t)gr * 64 + col] = (ushort)bf16rne(acc[cf][r]);
        }
    }
}

// ---------------------------------------------------------------------------
// part1: bin edges into NPC=98 coarse slabs (512 rows each). grid (625, 3).
// entry.x = col(16b) | rl(9b)<<16 | bin(7b)<<25 ; entry.y = fp32 val.
// LDS counting-sort per block -> flush runs of ~26 edges (208B) coalesced.
// ---------------------------------------------------------------------------
__global__ __launch_bounds__(256) void part1(const int*   __restrict__ rows,
                                             const int*   __restrict__ cols,
                                             const float* __restrict__ vals,
                                             int*   __restrict__ pcur3,
                                             uint2* __restrict__ coarsebuf)
{
    __shared__ uint2 stage[2560];     // 20 KB
    __shared__ uint2 sorted[2560];    // 20 KB
    __shared__ int cnt[128];
    __shared__ int sc[128];
    __shared__ int curb[128];
    __shared__ int gbase[128];
    const int t = threadIdx.x;
    const int path = blockIdx.y;
    const size_t ebase = (size_t)path * EE + (size_t)blockIdx.x * 2560;
    const int* rp = rows;  // offset applied via ebase
    int* pcur = pcur3 + path * NPC;
    uint2* cb = coarsebuf + (size_t)path * NPC * CCAP;

    if (t < 128) { cnt[t] = 0; curb[t] = 0; }
    __syncthreads();

    #pragma unroll
    for (int it = 0; it < 10; ++it) {
        int e = it * 256 + t;
        int r = rp[ebase + e];
        int c = cols[ebase + e];
        float v = vals[ebase + e];
        int bin = r >> 9, rl = r & 511;
        stage[e] = make_uint2((uint)c | ((uint)rl << 16) | ((uint)bin << 25),
                              __float_as_uint(v));
        atomicAdd(&cnt[bin], 1);
    }
    __syncthreads();

    if (t < 128) sc[t] = cnt[t];
    __syncthreads();
    #pragma unroll
    for (int o = 1; o < 128; o <<= 1) {
        int v = (t < 128 && t >= o) ? sc[t - o] : 0;
        __syncthreads();
        if (t < 128 && t >= o) sc[t] += v;
        __syncthreads();
    }
    // sc = inclusive scan; excl[b] = sc[b] - cnt[b]

    if (t < NPC) gbase[t] = atomicAdd(&pcur[t], cnt[t]);
    __syncthreads();

    #pragma unroll
    for (int it = 0; it < 10; ++it) {
        uint2 e = stage[it * 256 + t];
        int bin = e.x >> 25;
        int loc = (sc[bin] - cnt[bin]) + atomicAdd(&curb[bin], 1);
        sorted[loc] = e;
    }
    __syncthreads();

    #pragma unroll
    for (int it = 0; it < 10; ++it) {
        int i = it * 256 + t;
        uint2 e = sorted[i];
        int bin = e.x >> 25;
        int g = gbase[bin] + (i - (sc[bin] - cnt[bin]));
        if (g < CCAP) cb[(size_t)bin * CCAP + g] = e;
    }
}

// ---------------------------------------------------------------------------
// sort2: counting-sort each coarse slab by local row (512 bins). grid (98,3).
// Two linear passes over the slab; scattered writes confined to a ~140KB
// L2-local window. Emits rowbeg/rowend (absolute indices into sortbuf).
// ---------------------------------------------------------------------------
__global__ __launch_bounds__(512) void sort2(const uint2* __restrict__ coarsebuf,
                                             const int*   __restrict__ pcur3,
                                             uint2* __restrict__ sortbuf,
                                             int* __restrict__ rowbeg3,
                                             int* __restrict__ rowend3)
{
    __shared__ int hist[512];
    __shared__ int cur[512];
    const int t = threadIdx.x;
    const int c = blockIdx.x, path = blockIdx.y;
    const int n = min(pcur3[path * NPC + c], CCAP);
    const size_t slabbase = ((size_t)path * NPC + c) * CCAP;
    const uint2* src = coarsebuf + slabbase;

    hist[t] = 0;
    __syncthreads();

    for (int i = t; i < n; i += 512)
        atomicAdd(&hist[(src[i].x >> 16) & 511], 1);
    __syncthreads();

    int c0 = hist[t];
    __syncthreads();
    #pragma unroll
    for (int o = 1; o < 512; o <<= 1) {
        int v = (t >= o) ? hist[t - o] : 0;
        __syncthreads();
        hist[t] += v;
        __syncthreads();
    }
    int excl = hist[t] - c0;
    cur[t] = excl;
    int gr = c * 512 + t;
    if (gr < N_NODES) {
        rowbeg3[path * N_NODES + gr] = (int)(slabbase + excl);
        rowend3[path * N_NODES + gr] = (int)(slabbase + excl + c0);
    }
    __syncthreads();

    uint2* dst = sortbuf;
    for (int i = t; i < n; i += 512) {
        uint2 e = src[i];
        int rl = (e.x >> 16) & 511;
        int pos = atomicAdd(&cur[rl], 1);
        dst[slabbase + pos] = e;
    }
}

// ---------------------------------------------------------------------------
// Gather SpMM + bias + PReLU. grid (12500, 3). One wave per row;
// lane = (slot<<4)|dq: 4 edges in flight, 16 dim-quads, 8B bf16 s gathers.
// ---------------------------------------------------------------------------
__global__ __launch_bounds__(256) void spmm_gather(const uint2*  __restrict__ sortbuf,
                                                   const int*    __restrict__ rowbeg3,
                                                   const int*    __restrict__ rowend3,
                                                   const ushort* __restrict__ s_all,
                                                   const float*  __restrict__ bg,
                                                   const float*  __restrict__ alpha,
                                                   float* __restrict__ emb)
{
    const int path = blockIdx.y;
    const int wid = blockIdx.x * 4 + (threadIdx.x >> 6);
    const int lane = threadIdx.x & 63;
    const int dq = lane & 15, slot = lane >> 4;
    const int e0 = rowbeg3[path * N_NODES + wid];
    const int e1 = rowend3[path * N_NODES + wid];
    const ushort* s_p = s_all + (size_t)path * N_NODES * 64;

    float a0 = 0.f, a1 = 0.f, a2 = 0.f, a3 = 0.f;
    for (int e = e0; e < e1; e += 4) {
        int ee = e + slot;
        uint2 pk = (ee < e1) ? sortbuf[ee] : make_uint2(0u, 0u);  // val=0 harmless
        float v  = __uint_as_float(pk.y);
        uint col = pk.x & 0xffffu;
        uint2 g = *(const uint2*)&s_p[(size_t)col * 64 + dq * 4];
        a0 += v * __uint_as_float(g.x << 16);
        a1 += v * __uint_as_float(g.x & 0xffff0000u);
        a2 += v * __uint_as_float(g.y << 16);
        a3 += v * __uint_as_float(g.y & 0xffff0000u);
    }
    a0 += __shfl_xor(a0, 16); a0 += __shfl_xor(a0, 32);
    a1 += __shfl_xor(a1, 16); a1 += __shfl_xor(a1, 32);
    a2 += __shfl_xor(a2, 16); a2 += __shfl_xor(a2, 32);
    a3 += __shfl_xor(a3, 16); a3 += __shfl_xor(a3, 32);

    if (slot == 0) {
        const float al = alpha[path];
        const float* bgp = bg + path * 64;
        float4 o;
        o.x = a0 + bgp[dq * 4 + 0]; o.x = o.x > 0.f ? o.x : al * o.x;
        o.y = a1 + bgp[dq * 4 + 1]; o.y = o.y > 0.f ? o.y : al * o.y;
        o.z = a2 + bgp[dq * 4 + 2]; o.z = o.z > 0.f ? o.z : al * o.z;
        o.w = a3 + bgp[dq * 4 + 3]; o.w = o.w > 0.f ? o.w : al * o.w;
        *(float4*)&emb[((size_t)path * N_NODES + wid) * 64 + dq * 4] = o;
    }
}

// ---------------------------------------------------------------------------
// Attention partial sums: sp[p] += column-sums of tanh(emb_p @ Wa^T + ba)
// ---------------------------------------------------------------------------
__global__ __launch_bounds__(256) void postproc(const float* __restrict__ emb,
                                                const float* __restrict__ Wa,
                                                const float* __restrict__ ba,
                                                float* __restrict__ sp)
{
    __shared__ float Ws[64][64];
    __shared__ float As[64][64];
    __shared__ float red[16][64];
    const int t  = threadIdx.x;
    const int tx = t & 15;
    const int ty = t >> 4;
    const int nb = (N_NODES + 63) >> 6;
    const int p  = blockIdx.x / nb;
    const int tb = blockIdx.x % nb;
    const int row0 = tb * 64;
    const float* embp = emb + (size_t)p * N_NODES * 64;

    #pragma unroll
    for (int rep = 0; rep < 4; ++rep) {
        int id = rep * 1024 + t * 4;
        int e  = id >> 6;
        int k4 = id & 63;
        float4 wv = *(const float4*)&Wa[id];
        Ws[k4+0][e] = wv.x; Ws[k4+1][e] = wv.y;
        Ws[k4+2][e] = wv.z; Ws[k4+3][e] = wv.w;
    }
    #pragma unroll
    for (int rep = 0; rep < 4; ++rep) {
        int id = rep * 1024 + t * 4;
        int m  = id >> 6;
        int d4 = id & 63;
        int gr = row0 + m;
        int gr2 = gr < N_NODES ? gr : N_NODES - 1;
        float4 xv = *(const float4*)&embp[(size_t)gr2 * 64 + d4];
        As[d4+0][m] = xv.x; As[d4+1][m] = xv.y;
        As[d4+2][m] = xv.z; As[d4+3][m] = xv.w;
    }
    __syncthreads();

    float acc[4][4] = {};
    #pragma unroll 8
    for (int kk = 0; kk < 64; ++kk) {
        float4 a4 = *(const float4*)&As[kk][ty * 4];
        float4 b4 = *(const float4*)&Ws[kk][tx * 4];
        float av[4] = {a4.x, a4.y, a4.z, a4.w};
        float bv[4] = {b4.x, b4.y, b4.z, b4.w};
        #pragma unroll
        for (int i = 0; i < 4; ++i)
            #pragma unroll
            for (int j = 0; j < 4; ++j)
                acc[i][j] += av[i] * bv[j];
    }

    float colsum[4] = {0.f, 0.f, 0.f, 0.f};
    #pragma unroll
    for (int i = 0; i < 4; ++i) {
        int gr = row0 + ty * 4 + i;
        if (gr < N_NODES) {
            #pragma unroll
            for (int j = 0; j < 4; ++j)
                colsum[j] += tanhf(acc[i][j] + ba[tx * 4 + j]);
        }
    }
    #pragma unroll
    for (int j = 0; j < 4; ++j) red[ty][tx * 4 + j] = colsum[j];
    __syncthreads();
    if (t < 64) {
        float ssum = 0.f;
        #pragma unroll
        for (int g = 0; g < 16; ++g) ssum += red[g][t];
        unsafeAtomicAdd(&sp[p * 64 + t], ssum);
    }
}

// ---------------------------------------------------------------------------
__global__ void beta_kernel(const float* __restrict__ sp,
                            const float* __restrict__ att,
                            float* __restrict__ beta)
{
    int lane = threadIdx.x;   // 64 threads
    float w[PP];
    #pragma unroll
    for (int p = 0; p < PP; ++p) {
        float x = sp[p * 64 + lane] * (1.0f / (float)N_NODES) * att[lane];
        #pragma unroll
        for (int off = 32; off; off >>= 1) x += __shfl_down(x, off);
        w[p] = __shfl(x, 0);
    }
    if (lane == 0) {
        float mx = fmaxf(w[0], fmaxf(w[1], w[2]));
        float e0 = __expf(w[0] - mx);
        float e1 = __expf(w[1] - mx);
        float e2 = __expf(w[2] - mx);
        float s = e0 + e1 + e2;
        beta[0] = e0 / s; beta[1] = e1 / s; beta[2] = e2 / s;
    }
}

// ---------------------------------------------------------------------------
__global__ __launch_bounds__(256) void combine(const float* __restrict__ emb,
                                               const float* __restrict__ beta,
                                               float* __restrict__ out)
{
    const float b0 = beta[0], b1 = beta[1], b2 = beta[2];
    const size_t tot = (size_t)N_NODES * 64;
    size_t i = ((size_t)blockIdx.x * 256 + threadIdx.x) * 4;
    if (i < tot) {
        float4 e0 = *(const float4*)&emb[i];
        float4 e1 = *(const float4*)&emb[tot + i];
        float4 e2 = *(const float4*)&emb[2 * tot + i];
        float4 o;
        o.x = b0 * e0.x + b1 * e1.x + b2 * e2.x;
        o.y = b0 * e0.y + b1 * e1.y + b2 * e2.y;
        o.z = b0 * e0.z + b1 * e1.z + b2 * e2.z;
        o.w = b0 * e0.w + b1 * e1.w + b2 * e2.w;
        *(float4*)&out[i] = o;
    }
}

// ---------------------------------------------------------------------------
extern "C" void kernel_launch(void* const* d_in, const int* in_sizes, int n_in,
                              void* d_out, int out_size, void* d_ws, size_t ws_size,
                              hipStream_t stream)
{
    const float* feats = (const float*)d_in[0];
    const int*   rows  = (const int*)  d_in[1];
    const int*   cols  = (const int*)  d_in[2];
    const float* vals  = (const float*)d_in[3];
    const float* W0    = (const float*)d_in[4];
    const float* b0    = (const float*)d_in[5];
    const float* Wg    = (const float*)d_in[6];
    const float* bg    = (const float*)d_in[7];
    const float* alpha = (const float*)d_in[8];
    const float* Wa    = (const float*)d_in[9];
    const float* ba    = (const float*)d_in[10];
    const float* att   = (const float*)d_in[11];
    float* out = (float*)d_out;

    const size_t ND = (size_t)N_NODES * 64;      // 3.2M elements
    char* base = (char*)d_ws;
    float*  emb    = (float*)base;               base += 3 * ND * 4;        // 38.4 MB
    ushort* h_bf   = (ushort*)base;              base += ND * 2;            // 6.4 MB
    ushort* s_all  = (ushort*)base;              base += 3 * ND * 2;        // 19.2 MB
    ushort* W0h    = (ushort*)base;              base += 64 * 1024 * 2;
    ushort* Wgh    = (ushort*)base;              base += PP * 64 * 64 * 2;
    int*    pcur3  = (int*)base;                 base += PP * NPC * 4;      // 294 ints
    float*  sp     = (float*)base;               base += 192 * 4;
    float*  beta   = (float*)base;               base += 64 * 4;
    int*    rowbeg3 = (int*)base;                base += PP * N_NODES * 4;  // 600 KB
    int*    rowend3 = (int*)base;                base += PP * N_NODES * 4;  // 600 KB
    base = (char*)(((size_t)base + 255) & ~(size_t)255);
    uint2*  coarsebuf = (uint2*)base;            base += (size_t)PP * NPC * CCAP * 8;  // 41.5 MB
    uint2*  sortbuf   = (uint2*)base;            base += (size_t)PP * NPC * CCAP * 8;  // 41.5 MB

    // zero pcur3 + sp (contiguous)
    hipMemsetAsync(pcur3, 0, (PP * NPC + 192) * sizeof(int), stream);

    split_weights<<<(64 * 1024 + PP * 64 * 64 + 255) / 256, 256, 0, stream>>>(
        W0, Wg, W0h, Wgh);

    gemm1_mfma<<<782, 256, 0, stream>>>(feats, W0h, b0, h_bf);
    gemm_s<<<dim3(782, 3), 256, 0, stream>>>(h_bf, Wgh, s_all);

    part1<<<dim3(EE / 2560, 3), 256, 0, stream>>>(rows, cols, vals, pcur3, coarsebuf);
    sort2<<<dim3(NPC, 3), 512, 0, stream>>>(coarsebuf, pcur3, sortbuf, rowbeg3, rowend3);
    spmm_gather<<<dim3(N_NODES / 4, 3), 256, 0, stream>>>(
        sortbuf, rowbeg3, rowend3, s_all, bg, alpha, emb);

    postproc<<<3 * 782, 256, 0, stream>>>(emb, Wa, ba, sp);
    beta_kernel<<<1, 64, 0, stream>>>(sp, att, beta);
    combine<<<(int)(ND / 4 / 256), 256, 0, stream>>>(emb, beta, out);
}

// Round 7
// 340.661 us; speedup vs baseline: 6.7055x; 1.1514x over previous
//
#include <hip/hip_runtime.h>

#define N_NODES 50000
#define F_IN    1024
#define DD      64
#define PP      3
#define EE      1600000
#define NPC     98          // coarse partitions of 512 rows: (50000+511)/512
#define CCAP    17664       // slab capacity: mean 16384, sigma 128, +10 sigma

typedef __attribute__((ext_vector_type(8))) short short8v;   // 8 bf16 = 4 VGPR
typedef __attribute__((ext_vector_type(4))) float floatx4;

__device__ inline float bf16tof(uint u) { return __uint_as_float(u << 16); }
__device__ inline float bfl(uint u) { return __uint_as_float(u << 16); }
__device__ inline float bfh(uint u) { return __uint_as_float(u & 0xffff0000u); }
__device__ inline uint bf16rne(float x) {
    uint b = __float_as_uint(x);
    return (b + 0x7fffu + ((b >> 16) & 1u)) >> 16;
}

// ---------------------------------------------------------------------------
// Round W0 [64,1024] and Wg [3,64,64] to single bf16
// ---------------------------------------------------------------------------
__global__ __launch_bounds__(256) void split_weights(const float* __restrict__ W0,
                                                     const float* __restrict__ Wg,
                                                     ushort* __restrict__ W0h,
                                                     ushort* __restrict__ Wgh)
{
    int i = blockIdx.x * 256 + threadIdx.x;
    if (i < 64 * 1024) W0h[i] = (ushort)bf16rne(W0[i]);
    int j = i - 64 * 1024;
    if (j >= 0 && j < PP * 64 * 64) Wgh[j] = (ushort)bf16rne(Wg[j]);
}

// ---------------------------------------------------------------------------
// h = elu(feats @ W0^T + b0), single-bf16 MFMA 16x16x32.
// ---------------------------------------------------------------------------
__global__ __launch_bounds__(256) void gemm1_mfma(const float* __restrict__ feats,
                                                  const ushort* __restrict__ W0h,
                                                  const float* __restrict__ b0,
                                                  ushort* __restrict__ h_bf)
{
    __shared__ ushort Ah[64 * 64];   // 8 KB
    __shared__ ushort Bh[64 * 64];
    const int t = threadIdx.x;
    const int w = t >> 6, lane = t & 63;
    const int row0 = blockIdx.x * 64;
    const int l15 = lane & 15, l4 = lane >> 4;

    floatx4 acc[4] = {};

    for (int kc = 0; kc < 16; ++kc) {
        #pragma unroll
        for (int rep = 0; rep < 4; ++rep) {
            int idx = rep * 256 + t;             // 0..1023
            int r = idx >> 4, c4 = idx & 15;
            int gr = row0 + r; if (gr >= N_NODES) gr = N_NODES - 1;
            float4 v = *(const float4*)&feats[(size_t)gr * F_IN + kc * 64 + c4 * 4];
            uint h0 = bf16rne(v.x), h1 = bf16rne(v.y);
            uint h2 = bf16rne(v.z), h3 = bf16rne(v.w);
            int unit = (c4 >> 1) ^ (r & 7);
            int base = r * 64 + unit * 8 + (c4 & 1) * 4;
            *(uint2*)&Ah[base] = make_uint2(h0 | (h1 << 16), h2 | (h3 << 16));
        }
        #pragma unroll
        for (int rep = 0; rep < 2; ++rep) {
            int idx = rep * 256 + t;             // 0..511
            int c = idx >> 3, u8 = idx & 7;
            uint4 vh = *(const uint4*)&W0h[(size_t)c * F_IN + kc * 64 + u8 * 8];
            int unit = u8 ^ (c & 7);
            *(uint4*)&Bh[c * 64 + unit * 8] = vh;
        }
        __syncthreads();
        #pragma unroll
        for (int ks = 0; ks < 2; ++ks) {
            int arow = w * 16 + l15;
            int au = (ks * 4 + l4) ^ (arow & 7);
            short8v ah = *(short8v*)&Ah[arow * 64 + au * 8];
            #pragma unroll
            for (int cf = 0; cf < 4; ++cf) {
                int bcol = cf * 16 + l15;
                int bu = (ks * 4 + l4) ^ (bcol & 7);
                short8v bh = *(short8v*)&Bh[bcol * 64 + bu * 8];
                acc[cf] = __builtin_amdgcn_mfma_f32_16x16x32_bf16(ah, bh, acc[cf], 0, 0, 0);
            }
        }
        __syncthreads();
    }

    #pragma unroll
    for (int cf = 0; cf < 4; ++cf) {
        int col = cf * 16 + l15;
        #pragma unroll
        for (int r = 0; r < 4; ++r) {
            int gr = row0 + w * 16 + l4 * 4 + r;
            if (gr < N_NODES) {
                float x = acc[cf][r] + b0[col];
                x = x > 0.f ? x : (__expf(x) - 1.f);
                h_bf[(size_t)gr * 64 + col] = (ushort)bf16rne(x);
            }
        }
    }
}

// ---------------------------------------------------------------------------
// s[p] = h @ Wg[p]^T  (single-bf16 MFMA, K=64), output bf16. grid (782,3)
// ---------------------------------------------------------------------------
__global__ __launch_bounds__(256) void gemm_s(const ushort* __restrict__ h_bf,
                                              const ushort* __restrict__ Wgh,
                                              ushort* __restrict__ s_all)
{
    __shared__ ushort Ah[64 * 64];
    __shared__ ushort Bh[64 * 64];
    const int t = threadIdx.x;
    const int w = t >> 6, lane = t & 63;
    const int p = blockIdx.y;
    const int row0 = blockIdx.x * 64;
    const int l15 = lane & 15, l4 = lane >> 4;

    #pragma unroll
    for (int rep = 0; rep < 2; ++rep) {
        int idx = rep * 256 + t;                 // 0..511
        int r = idx >> 3, u8 = idx & 7;
        int gr = row0 + r; if (gr >= N_NODES) gr = N_NODES - 1;
        int unit = u8 ^ (r & 7);
        *(uint4*)&Ah[r * 64 + unit * 8] = *(const uint4*)&h_bf[(size_t)gr * 64 + u8 * 8];
        *(uint4*)&Bh[r * 64 + unit * 8] = *(const uint4*)&Wgh[(size_t)p * 4096 + idx * 8];
    }
    __syncthreads();

    floatx4 acc[4] = {};
    #pragma unroll
    for (int ks = 0; ks < 2; ++ks) {
        int arow = w * 16 + l15;
        int au = (ks * 4 + l4) ^ (arow & 7);
        short8v ah = *(short8v*)&Ah[arow * 64 + au * 8];
        #pragma unroll
        for (int cf = 0; cf < 4; ++cf) {
            int bcol = cf * 16 + l15;
            int bu = (ks * 4 + l4) ^ (bcol & 7);
            short8v bh = *(short8v*)&Bh[bcol * 64 + bu * 8];
            acc[cf] = __builtin_amdgcn_mfma_f32_16x16x32_bf16(ah, bh, acc[cf], 0, 0, 0);
        }
    }

    ushort* sp = s_all + (size_t)p * N_NODES * 64;
    #pragma unroll
    for (int cf = 0; cf < 4; ++cf) {
        int col = cf * 16 + l15;
        #pragma unroll
        for (int r = 0; r < 4; ++r) {
            int gr = row0 + w * 16 + l4 * 4 + r;
            if (gr < N_NODES)
                sp[(size_t)gr * 64 + col] = (ushort)bf16rne(acc[cf][r]);
        }
    }
}

// ---------------------------------------------------------------------------
// part1: bin edges into NPC=98 coarse slabs (512 rows each). grid (625, 3).
// entry.x = col(16b) | rl(9b)<<16 | bin(7b)<<25 ; entry.y = fp32 val.
// ---------------------------------------------------------------------------
__global__ __launch_bounds__(256) void part1(const int*   __restrict__ rows,
                                             const int*   __restrict__ cols,
                                             const float* __restrict__ vals,
                                             int*   __restrict__ pcur3,
                                             uint2* __restrict__ coarsebuf)
{
    __shared__ uint2 stage[2560];     // 20 KB
    __shared__ uint2 sorted[2560];    // 20 KB
    __shared__ int cnt[128];
    __shared__ int sc[128];
    __shared__ int curb[128];
    __shared__ int gbase[128];
    const int t = threadIdx.x;
    const int path = blockIdx.y;
    const size_t ebase = (size_t)path * EE + (size_t)blockIdx.x * 2560;
    int* pcur = pcur3 + path * NPC;
    uint2* cb = coarsebuf + (size_t)path * NPC * CCAP;

    if (t < 128) { cnt[t] = 0; curb[t] = 0; }
    __syncthreads();

    #pragma unroll
    for (int it = 0; it < 10; ++it) {
        int e = it * 256 + t;
        int r = rows[ebase + e];
        int c = cols[ebase + e];
        float v = vals[ebase + e];
        int bin = r >> 9, rl = r & 511;
        stage[e] = make_uint2((uint)c | ((uint)rl << 16) | ((uint)bin << 25),
                              __float_as_uint(v));
        atomicAdd(&cnt[bin], 1);
    }
    __syncthreads();

    if (t < 128) sc[t] = cnt[t];
    __syncthreads();
    #pragma unroll
    for (int o = 1; o < 128; o <<= 1) {
        int v = (t < 128 && t >= o) ? sc[t - o] : 0;
        __syncthreads();
        if (t < 128 && t >= o) sc[t] += v;
        __syncthreads();
    }

    if (t < NPC) gbase[t] = atomicAdd(&pcur[t], cnt[t]);
    __syncthreads();

    #pragma unroll
    for (int it = 0; it < 10; ++it) {
        uint2 e = stage[it * 256 + t];
        int bin = e.x >> 25;
        int loc = (sc[bin] - cnt[bin]) + atomicAdd(&curb[bin], 1);
        sorted[loc] = e;
    }
    __syncthreads();

    #pragma unroll
    for (int it = 0; it < 10; ++it) {
        int i = it * 256 + t;
        uint2 e = sorted[i];
        int bin = e.x >> 25;
        int g = gbase[bin] + (i - (sc[bin] - cnt[bin]));
        if (g < CCAP) cb[(size_t)bin * CCAP + g] = e;
    }
}

// ---------------------------------------------------------------------------
// sort2: counting-sort each coarse slab by local row (512 bins). grid (98,3).
// ---------------------------------------------------------------------------
__global__ __launch_bounds__(512) void sort2(const uint2* __restrict__ coarsebuf,
                                             const int*   __restrict__ pcur3,
                                             uint2* __restrict__ sortbuf,
                                             int* __restrict__ rowbeg3,
                                             int* __restrict__ rowend3)
{
    __shared__ int hist[512];
    __shared__ int cur[512];
    const int t = threadIdx.x;
    const int c = blockIdx.x, path = blockIdx.y;
    const int n = min(pcur3[path * NPC + c], CCAP);
    const size_t slabbase = ((size_t)path * NPC + c) * CCAP;
    const uint2* src = coarsebuf + slabbase;

    hist[t] = 0;
    __syncthreads();

    for (int i = t; i < n; i += 512)
        atomicAdd(&hist[(src[i].x >> 16) & 511], 1);
    __syncthreads();

    int c0 = hist[t];
    __syncthreads();
    #pragma unroll
    for (int o = 1; o < 512; o <<= 1) {
        int v = (t >= o) ? hist[t - o] : 0;
        __syncthreads();
        hist[t] += v;
        __syncthreads();
    }
    int excl = hist[t] - c0;
    cur[t] = excl;
    int gr = c * 512 + t;
    if (gr < N_NODES) {
        rowbeg3[path * N_NODES + gr] = (int)(slabbase + excl);
        rowend3[path * N_NODES + gr] = (int)(slabbase + excl + c0);
    }
    __syncthreads();

    for (int i = t; i < n; i += 512) {
        uint2 e = src[i];
        int rl = (e.x >> 16) & 511;
        int pos = atomicAdd(&cur[rl], 1);
        sortbuf[slabbase + pos] = e;
    }
}

// ---------------------------------------------------------------------------
// Gather SpMM + bias + PReLU. grid (12500, 3). One wave per row.
// lane = (slot<<3)|dq: 8 edge slots x 8 dim-octets (16B uint4 gathers).
// Unroll x4 -> 32 edges in flight per wave-iteration. Output emb in bf16.
// ---------------------------------------------------------------------------
__global__ __launch_bounds__(256) void spmm_gather(const uint2*  __restrict__ sortbuf,
                                                   const int*    __restrict__ rowbeg3,
                                                   const int*    __restrict__ rowend3,
                                                   const ushort* __restrict__ s_all,
                                                   const float*  __restrict__ bg,
                                                   const float*  __restrict__ alpha,
                                                   ushort* __restrict__ emb)
{
    const int path = blockIdx.y;
    const int wid = blockIdx.x * 4 + (threadIdx.x >> 6);
    const int lane = threadIdx.x & 63;
    const int dq = lane & 7;          // dim-octet: dims [dq*8, dq*8+8)
    const int slot = lane >> 3;       // 8 edge slots
    const int e0 = rowbeg3[path * N_NODES + wid];
    const int e1 = rowend3[path * N_NODES + wid];
    const ushort* s_p = s_all + (size_t)path * N_NODES * 64;

    float acc[8] = {};
    for (int e = e0; e < e1; e += 32) {
        int ea = e + slot, eb = ea + 8, ec = ea + 16, ed = ea + 24;
        uint2 pka = (ea < e1) ? sortbuf[ea] : make_uint2(0u, 0u);
        uint2 pkb = (eb < e1) ? sortbuf[eb] : make_uint2(0u, 0u);
        uint2 pkc = (ec < e1) ? sortbuf[ec] : make_uint2(0u, 0u);
        uint2 pkd = (ed < e1) ? sortbuf[ed] : make_uint2(0u, 0u);
        uint4 ga = *(const uint4*)&s_p[(size_t)(pka.x & 0xffffu) * 64 + dq * 8];
        uint4 gb = *(const uint4*)&s_p[(size_t)(pkb.x & 0xffffu) * 64 + dq * 8];
        uint4 gc = *(const uint4*)&s_p[(size_t)(pkc.x & 0xffffu) * 64 + dq * 8];
        uint4 gd = *(const uint4*)&s_p[(size_t)(pkd.x & 0xffffu) * 64 + dq * 8];
        float va = __uint_as_float(pka.y);
        float vb = __uint_as_float(pkb.y);
        float vc = __uint_as_float(pkc.y);
        float vd = __uint_as_float(pkd.y);
        acc[0] += va * bfl(ga.x); acc[1] += va * bfh(ga.x);
        acc[2] += va * bfl(ga.y); acc[3] += va * bfh(ga.y);
        acc[4] += va * bfl(ga.z); acc[5] += va * bfh(ga.z);
        acc[6] += va * bfl(ga.w); acc[7] += va * bfh(ga.w);
        acc[0] += vb * bfl(gb.x); acc[1] += vb * bfh(gb.x);
        acc[2] += vb * bfl(gb.y); acc[3] += vb * bfh(gb.y);
        acc[4] += vb * bfl(gb.z); acc[5] += vb * bfh(gb.z);
        acc[6] += vb * bfl(gb.w); acc[7] += vb * bfh(gb.w);
        acc[0] += vc * bfl(gc.x); acc[1] += vc * bfh(gc.x);
        acc[2] += vc * bfl(gc.y); acc[3] += vc * bfh(gc.y);
        acc[4] += vc * bfl(gc.z); acc[5] += vc * bfh(gc.z);
        acc[6] += vc * bfl(gc.w); acc[7] += vc * bfh(gc.w);
        acc[0] += vd * bfl(gd.x); acc[1] += vd * bfh(gd.x);
        acc[2] += vd * bfl(gd.y); acc[3] += vd * bfh(gd.y);
        acc[4] += vd * bfl(gd.z); acc[5] += vd * bfh(gd.z);
        acc[6] += vd * bfl(gd.w); acc[7] += vd * bfh(gd.w);
    }
    #pragma unroll
    for (int j = 0; j < 8; ++j) {
        acc[j] += __shfl_xor(acc[j], 8);
        acc[j] += __shfl_xor(acc[j], 16);
        acc[j] += __shfl_xor(acc[j], 32);
    }

    if (slot == 0) {   // lanes 0..7 hold dims [dq*8, dq*8+8)
        const float al = alpha[path];
        const float* bgp = bg + path * 64;
        uint pk0[8];
        #pragma unroll
        for (int j = 0; j < 8; ++j) {
            float x = acc[j] + bgp[dq * 8 + j];
            x = x > 0.f ? x : al * x;
            pk0[j] = bf16rne(x);
        }
        uint4 wv;
        wv.x = pk0[0] | (pk0[1] << 16);
        wv.y = pk0[2] | (pk0[3] << 16);
        wv.z = pk0[4] | (pk0[5] << 16);
        wv.w = pk0[6] | (pk0[7] << 16);
        *(uint4*)&emb[((size_t)path * N_NODES + wid) * 64 + dq * 8] = wv;
    }
}

// ---------------------------------------------------------------------------
// Attention partial sums: sp[p] += column-sums of tanh(emb_p @ Wa^T + ba)
// emb is bf16 now.
// ---------------------------------------------------------------------------
__global__ __launch_bounds__(256) void postproc(const ushort* __restrict__ emb,
                                                const float* __restrict__ Wa,
                                                const float* __restrict__ ba,
                                                float* __restrict__ sp)
{
    __shared__ float Ws[64][64];
    __shared__ float As[64][64];
    __shared__ float red[16][64];
    const int t  = threadIdx.x;
    const int tx = t & 15;
    const int ty = t >> 4;
    const int nb = (N_NODES + 63) >> 6;
    const int p  = blockIdx.x / nb;
    const int tb = blockIdx.x % nb;
    const int row0 = tb * 64;
    const ushort* embp = emb + (size_t)p * N_NODES * 64;

    #pragma unroll
    for (int rep = 0; rep < 4; ++rep) {
        int id = rep * 1024 + t * 4;
        int e  = id >> 6;
        int k4 = id & 63;
        float4 wv = *(const float4*)&Wa[id];
        Ws[k4+0][e] = wv.x; Ws[k4+1][e] = wv.y;
        Ws[k4+2][e] = wv.z; Ws[k4+3][e] = wv.w;
    }
    #pragma unroll
    for (int rep = 0; rep < 2; ++rep) {
        int idx = rep * 256 + t;      // 0..511
        int m  = idx >> 3;
        int d8 = idx & 7;
        int gr = row0 + m;
        int gr2 = gr < N_NODES ? gr : N_NODES - 1;
        uint4 xv = *(const uint4*)&embp[(size_t)gr2 * 64 + d8 * 8];
        As[d8*8+0][m] = bfl(xv.x); As[d8*8+1][m] = bfh(xv.x);
        As[d8*8+2][m] = bfl(xv.y); As[d8*8+3][m] = bfh(xv.y);
        As[d8*8+4][m] = bfl(xv.z); As[d8*8+5][m] = bfh(xv.z);
        As[d8*8+6][m] = bfl(xv.w); As[d8*8+7][m] = bfh(xv.w);
    }
    __syncthreads();

    float acc[4][4] = {};
    #pragma unroll 8
    for (int kk = 0; kk < 64; ++kk) {
        float4 a4 = *(const float4*)&As[kk][ty * 4];
        float4 b4 = *(const float4*)&Ws[kk][tx * 4];
        float av[4] = {a4.x, a4.y, a4.z, a4.w};
        float bv[4] = {b4.x, b4.y, b4.z, b4.w};
        #pragma unroll
        for (int i = 0; i < 4; ++i)
            #pragma unroll
            for (int j = 0; j < 4; ++j)
                acc[i][j] += av[i] * bv[j];
    }

    float colsum[4] = {0.f, 0.f, 0.f, 0.f};
    #pragma unroll
    for (int i = 0; i < 4; ++i) {
        int gr = row0 + ty * 4 + i;
        if (gr < N_NODES) {
            #pragma unroll
            for (int j = 0; j < 4; ++j)
                colsum[j] += tanhf(acc[i][j] + ba[tx * 4 + j]);
        }
    }
    #pragma unroll
    for (int j = 0; j < 4; ++j) red[ty][tx * 4 + j] = colsum[j];
    __syncthreads();
    if (t < 64) {
        float ssum = 0.f;
        #pragma unroll
        for (int g = 0; g < 16; ++g) ssum += red[g][t];
        unsafeAtomicAdd(&sp[p * 64 + t], ssum);
    }
}

// ---------------------------------------------------------------------------
__global__ void beta_kernel(const float* __restrict__ sp,
                            const float* __restrict__ att,
                            float* __restrict__ beta)
{
    int lane = threadIdx.x;   // 64 threads
    float w[PP];
    #pragma unroll
    for (int p = 0; p < PP; ++p) {
        float x = sp[p * 64 + lane] * (1.0f / (float)N_NODES) * att[lane];
        #pragma unroll
        for (int off = 32; off; off >>= 1) x += __shfl_down(x, off);
        w[p] = __shfl(x, 0);
    }
    if (lane == 0) {
        float mx = fmaxf(w[0], fmaxf(w[1], w[2]));
        float e0 = __expf(w[0] - mx);
        float e1 = __expf(w[1] - mx);
        float e2 = __expf(w[2] - mx);
        float s = e0 + e1 + e2;
        beta[0] = e0 / s; beta[1] = e1 / s; beta[2] = e2 / s;
    }
}

// ---------------------------------------------------------------------------
// z[n][d] = sum_p beta[p] * emb[p][n][d]   (emb bf16, out fp32)
// ---------------------------------------------------------------------------
__global__ __launch_bounds__(256) void combine(const ushort* __restrict__ emb,
                                               const float* __restrict__ beta,
                                               float* __restrict__ out)
{
    const float b0 = beta[0], b1 = beta[1], b2 = beta[2];
    const size_t tot = (size_t)N_NODES * 64;
    size_t i = ((size_t)blockIdx.x * 256 + threadIdx.x) * 8;
    if (i < tot) {
        uint4 e0 = *(const uint4*)&emb[i];
        uint4 e1 = *(const uint4*)&emb[tot + i];
        uint4 e2 = *(const uint4*)&emb[2 * tot + i];
        float o[8];
        o[0] = b0*bfl(e0.x) + b1*bfl(e1.x) + b2*bfl(e2.x);
        o[1] = b0*bfh(e0.x) + b1*bfh(e1.x) + b2*bfh(e2.x);
        o[2] = b0*bfl(e0.y) + b1*bfl(e1.y) + b2*bfl(e2.y);
        o[3] = b0*bfh(e0.y) + b1*bfh(e1.y) + b2*bfh(e2.y);
        o[4] = b0*bfl(e0.z) + b1*bfl(e1.z) + b2*bfl(e2.z);
        o[5] = b0*bfh(e0.z) + b1*bfh(e1.z) + b2*bfh(e2.z);
        o[6] = b0*bfl(e0.w) + b1*bfl(e1.w) + b2*bfl(e2.w);
        o[7] = b0*bfh(e0.w) + b1*bfh(e1.w) + b2*bfh(e2.w);
        *(float4*)&out[i]     = make_float4(o[0], o[1], o[2], o[3]);
        *(float4*)&out[i + 4] = make_float4(o[4], o[5], o[6], o[7]);
    }
}

// ---------------------------------------------------------------------------
extern "C" void kernel_launch(void* const* d_in, const int* in_sizes, int n_in,
                              void* d_out, int out_size, void* d_ws, size_t ws_size,
                              hipStream_t stream)
{
    const float* feats = (const float*)d_in[0];
    const int*   rows  = (const int*)  d_in[1];
    const int*   cols  = (const int*)  d_in[2];
    const float* vals  = (const float*)d_in[3];
    const float* W0    = (const float*)d_in[4];
    const float* b0    = (const float*)d_in[5];
    const float* Wg    = (const float*)d_in[6];
    const float* bg    = (const float*)d_in[7];
    const float* alpha = (const float*)d_in[8];
    const float* Wa    = (const float*)d_in[9];
    const float* ba    = (const float*)d_in[10];
    const float* att   = (const float*)d_in[11];
    float* out = (float*)d_out;

    const size_t ND = (size_t)N_NODES * 64;      // 3.2M elements
    char* base = (char*)d_ws;
    ushort* emb    = (ushort*)base;              base += 3 * ND * 2;        // 19.2 MB
    ushort* h_bf   = (ushort*)base;              base += ND * 2;            // 6.4 MB
    ushort* s_all  = (ushort*)base;              base += 3 * ND * 2;        // 19.2 MB
    ushort* W0h    = (ushort*)base;              base += 64 * 1024 * 2;
    ushort* Wgh    = (ushort*)base;              base += PP * 64 * 64 * 2;
    int*    pcur3  = (int*)base;                 base += PP * NPC * 4;
    float*  sp     = (float*)base;               base += 192 * 4;
    float*  beta   = (float*)base;               base += 64 * 4;
    int*    rowbeg3 = (int*)base;                base += PP * N_NODES * 4;  // 600 KB
    int*    rowend3 = (int*)base;                base += PP * N_NODES * 4;  // 600 KB
    base = (char*)(((size_t)base + 255) & ~(size_t)255);
    uint2*  coarsebuf = (uint2*)base;            base += (size_t)PP * NPC * CCAP * 8;  // 41.5 MB
    uint2*  sortbuf   = (uint2*)base;            base += (size_t)PP * NPC * CCAP * 8;  // 41.5 MB

    // zero pcur3 + sp (contiguous)
    hipMemsetAsync(pcur3, 0, (PP * NPC + 192) * sizeof(int), stream);

    split_weights<<<(64 * 1024 + PP * 64 * 64 + 255) / 256, 256, 0, stream>>>(
        W0, Wg, W0h, Wgh);

    gemm1_mfma<<<782, 256, 0, stream>>>(feats, W0h, b0, h_bf);
    gemm_s<<<dim3(782, 3), 256, 0, stream>>>(h_bf, Wgh, s_all);

    part1<<<dim3(EE / 2560, 3), 256, 0, stream>>>(rows, cols, vals, pcur3, coarsebuf);
    sort2<<<dim3(NPC, 3), 512, 0, stream>>>(coarsebuf, pcur3, sortbuf, rowbeg3, rowend3);
    spmm_gather<<<dim3(N_NODES / 4, 3), 256, 0, stream>>>(
        sortbuf, rowbeg3, rowend3, s_all, bg, alpha, emb);

    postproc<<<3 * 782, 256, 0, stream>>>(emb, Wa, ba, sp);
    beta_kernel<<<1, 64, 0, stream>>>(sp, att, beta);
    combine<<<(int)((ND / 8 + 255) / 256), 256, 0, stream>>>(emb, beta, out);
}

// Round 8
// 318.745 us; speedup vs baseline: 7.1665x; 1.0688x over previous
//
#include <hip/hip_runtime.h>
#include <hip/hip_bf16.h>

#define N_NODES 50000
#define F_IN    1024
#define DD      64
#define PP      3
#define EE      1600000
#define NPC     98          // coarse partitions of 512 rows: (50000+511)/512
#define CCAP    17664       // slab capacity: mean 16384, sigma 128, +10 sigma

typedef __attribute__((ext_vector_type(8))) short short8v;   // 8 bf16 = 4 VGPR
typedef __attribute__((ext_vector_type(4))) float floatx4;

__device__ inline float bfl(uint u) { return __uint_as_float(u << 16); }
__device__ inline float bfh(uint u) { return __uint_as_float(u & 0xffff0000u); }
// packed 2xf32 -> 2xbf16 (RNE) via v_cvt_pk_bf16_f32; intrinsic so the
// compiler schedules it (m240: inline-asm cvt_pk defeats scheduling)
__device__ inline uint cvtpk2(float a, float b) {
    __hip_bfloat162 h = __float22bfloat162_rn(make_float2(a, b));
    return *(uint*)&h;
}
__device__ inline ushort f2bf(float x) {
    __hip_bfloat16 h = __float2bfloat16(x);
    return *(ushort*)&h;
}

// ---------------------------------------------------------------------------
// Round W0 [64,1024] and Wg [3,64,64] to single bf16
// ---------------------------------------------------------------------------
__global__ __launch_bounds__(256) void split_weights(const float* __restrict__ W0,
                                                     const float* __restrict__ Wg,
                                                     ushort* __restrict__ W0h,
                                                     ushort* __restrict__ Wgh)
{
    int i = blockIdx.x * 256 + threadIdx.x;
    if (i < 64 * 1024) W0h[i] = f2bf(W0[i]);
    int j = i - 64 * 1024;
    if (j >= 0 && j < PP * 64 * 64) Wgh[j] = f2bf(Wg[j]);
}

// ---------------------------------------------------------------------------
// h = elu(feats @ W0^T + b0), single-bf16 MFMA 16x16x32.
// Staging conversion via packed v_cvt_pk_bf16_f32 (2 VALU per float4).
// ---------------------------------------------------------------------------
__global__ __launch_bounds__(256) void gemm1_mfma(const float* __restrict__ feats,
                                                  const ushort* __restrict__ W0h,
                                                  const float* __restrict__ b0,
                                                  ushort* __restrict__ h_bf)
{
    __shared__ ushort Ah[64 * 64];   // 8 KB
    __shared__ ushort Bh[64 * 64];
    const int t = threadIdx.x;
    const int w = t >> 6, lane = t & 63;
    const int row0 = blockIdx.x * 64;
    const int l15 = lane & 15, l4 = lane >> 4;

    floatx4 acc[4] = {};

    for (int kc = 0; kc < 16; ++kc) {
        #pragma unroll
        for (int rep = 0; rep < 4; ++rep) {
            int idx = rep * 256 + t;             // 0..1023
            int r = idx >> 4, c4 = idx & 15;
            int gr = row0 + r; if (gr >= N_NODES) gr = N_NODES - 1;
            float4 v = *(const float4*)&feats[(size_t)gr * F_IN + kc * 64 + c4 * 4];
            int unit = (c4 >> 1) ^ (r & 7);
            int base = r * 64 + unit * 8 + (c4 & 1) * 4;
            *(uint2*)&Ah[base] = make_uint2(cvtpk2(v.x, v.y), cvtpk2(v.z, v.w));
        }
        #pragma unroll
        for (int rep = 0; rep < 2; ++rep) {
            int idx = rep * 256 + t;             // 0..511
            int c = idx >> 3, u8 = idx & 7;
            uint4 vh = *(const uint4*)&W0h[(size_t)c * F_IN + kc * 64 + u8 * 8];
            int unit = u8 ^ (c & 7);
            *(uint4*)&Bh[c * 64 + unit * 8] = vh;
        }
        __syncthreads();
        #pragma unroll
        for (int ks = 0; ks < 2; ++ks) {
            int arow = w * 16 + l15;
            int au = (ks * 4 + l4) ^ (arow & 7);
            short8v ah = *(short8v*)&Ah[arow * 64 + au * 8];
            #pragma unroll
            for (int cf = 0; cf < 4; ++cf) {
                int bcol = cf * 16 + l15;
                int bu = (ks * 4 + l4) ^ (bcol & 7);
                short8v bh = *(short8v*)&Bh[bcol * 64 + bu * 8];
                acc[cf] = __builtin_amdgcn_mfma_f32_16x16x32_bf16(ah, bh, acc[cf], 0, 0, 0);
            }
        }
        __syncthreads();
    }

    #pragma unroll
    for (int cf = 0; cf < 4; ++cf) {
        int col = cf * 16 + l15;
        #pragma unroll
        for (int r = 0; r < 4; ++r) {
            int gr = row0 + w * 16 + l4 * 4 + r;
            if (gr < N_NODES) {
                float x = acc[cf][r] + b0[col];
                x = x > 0.f ? x : (__expf(x) - 1.f);
                h_bf[(size_t)gr * 64 + col] = f2bf(x);
            }
        }
    }
}

// ---------------------------------------------------------------------------
// s[p] = h @ Wg[p]^T  (single-bf16 MFMA, K=64), output bf16. grid (782,3)
// ---------------------------------------------------------------------------
__global__ __launch_bounds__(256) void gemm_s(const ushort* __restrict__ h_bf,
                                              const ushort* __restrict__ Wgh,
                                              ushort* __restrict__ s_all)
{
    __shared__ ushort Ah[64 * 64];
    __shared__ ushort Bh[64 * 64];
    const int t = threadIdx.x;
    const int w = t >> 6, lane = t & 63;
    const int p = blockIdx.y;
    const int row0 = blockIdx.x * 64;
    const int l15 = lane & 15, l4 = lane >> 4;

    #pragma unroll
    for (int rep = 0; rep < 2; ++rep) {
        int idx = rep * 256 + t;                 // 0..511
        int r = idx >> 3, u8 = idx & 7;
        int gr = row0 + r; if (gr >= N_NODES) gr = N_NODES - 1;
        int unit = u8 ^ (r & 7);
        *(uint4*)&Ah[r * 64 + unit * 8] = *(const uint4*)&h_bf[(size_t)gr * 64 + u8 * 8];
        *(uint4*)&Bh[r * 64 + unit * 8] = *(const uint4*)&Wgh[(size_t)p * 4096 + idx * 8];
    }
    __syncthreads();

    floatx4 acc[4] = {};
    #pragma unroll
    for (int ks = 0; ks < 2; ++ks) {
        int arow = w * 16 + l15;
        int au = (ks * 4 + l4) ^ (arow & 7);
        short8v ah = *(short8v*)&Ah[arow * 64 + au * 8];
        #pragma unroll
        for (int cf = 0; cf < 4; ++cf) {
            int bcol = cf * 16 + l15;
            int bu = (ks * 4 + l4) ^ (bcol & 7);
            short8v bh = *(short8v*)&Bh[bcol * 64 + bu * 8];
            acc[cf] = __builtin_amdgcn_mfma_f32_16x16x32_bf16(ah, bh, acc[cf], 0, 0, 0);
        }
    }

    ushort* sp = s_all + (size_t)p * N_NODES * 64;
    #pragma unroll
    for (int cf = 0; cf < 4; ++cf) {
        int col = cf * 16 + l15;
        #pragma unroll
        for (int r = 0; r < 4; ++r) {
            int gr = row0 + w * 16 + l4 * 4 + r;
            if (gr < N_NODES)
                sp[(size_t)gr * 64 + col] = f2bf(acc[cf][r]);
        }
    }
}

// ---------------------------------------------------------------------------
// part1: bin edges into NPC=98 coarse slabs (512 rows each). grid (625, 3).
// entry.x = col(16b) | rl(9b)<<16 | bin(7b)<<25 ; entry.y = fp32 val.
// ---------------------------------------------------------------------------
__global__ __launch_bounds__(256) void part1(const int*   __restrict__ rows,
                                             const int*   __restrict__ cols,
                                             const float* __restrict__ vals,
                                             int*   __restrict__ pcur3,
                                             uint2* __restrict__ coarsebuf)
{
    __shared__ uint2 stage[2560];     // 20 KB
    __shared__ uint2 sorted[2560];    // 20 KB
    __shared__ int cnt[128];
    __shared__ int sc[128];
    __shared__ int curb[128];
    __shared__ int gbase[128];
    const int t = threadIdx.x;
    const int path = blockIdx.y;
    const size_t ebase = (size_t)path * EE + (size_t)blockIdx.x * 2560;
    int* pcur = pcur3 + path * NPC;
    uint2* cb = coarsebuf + (size_t)path * NPC * CCAP;

    if (t < 128) { cnt[t] = 0; curb[t] = 0; }
    __syncthreads();

    #pragma unroll
    for (int it = 0; it < 10; ++it) {
        int e = it * 256 + t;
        int r = rows[ebase + e];
        int c = cols[ebase + e];
        float v = vals[ebase + e];
        int bin = r >> 9, rl = r & 511;
        stage[e] = make_uint2((uint)c | ((uint)rl << 16) | ((uint)bin << 25),
                              __float_as_uint(v));
        atomicAdd(&cnt[bin], 1);
    }
    __syncthreads();

    if (t < 128) sc[t] = cnt[t];
    __syncthreads();
    #pragma unroll
    for (int o = 1; o < 128; o <<= 1) {
        int v = (t < 128 && t >= o) ? sc[t - o] : 0;
        __syncthreads();
        if (t < 128 && t >= o) sc[t] += v;
        __syncthreads();
    }

    if (t < NPC) gbase[t] = atomicAdd(&pcur[t], cnt[t]);
    __syncthreads();

    #pragma unroll
    for (int it = 0; it < 10; ++it) {
        uint2 e = stage[it * 256 + t];
        int bin = e.x >> 25;
        int loc = (sc[bin] - cnt[bin]) + atomicAdd(&curb[bin], 1);
        sorted[loc] = e;
    }
    __syncthreads();

    #pragma unroll
    for (int it = 0; it < 10; ++it) {
        int i = it * 256 + t;
        uint2 e = sorted[i];
        int bin = e.x >> 25;
        int g = gbase[bin] + (i - (sc[bin] - cnt[bin]));
        if (g < CCAP) cb[(size_t)bin * CCAP + g] = e;
    }
}

// ---------------------------------------------------------------------------
// sort2: counting-sort each coarse slab by local row (512 bins). grid (98,3).
// Output entries packed to 4B: col(16b) | bf16(val)<<16 — rl is implied by
// rowbeg/rowend after sorting.
// ---------------------------------------------------------------------------
__global__ __launch_bounds__(512) void sort2(const uint2* __restrict__ coarsebuf,
                                             const int*   __restrict__ pcur3,
                                             uint* __restrict__ sortpk,
                                             int* __restrict__ rowbeg3,
                                             int* __restrict__ rowend3)
{
    __shared__ int hist[512];
    __shared__ int cur[512];
    const int t = threadIdx.x;
    const int c = blockIdx.x, path = blockIdx.y;
    const int n = min(pcur3[path * NPC + c], CCAP);
    const size_t slabbase = ((size_t)path * NPC + c) * CCAP;
    const uint2* src = coarsebuf + slabbase;

    hist[t] = 0;
    __syncthreads();

    for (int i = t; i < n; i += 512)
        atomicAdd(&hist[(src[i].x >> 16) & 511], 1);
    __syncthreads();

    int c0 = hist[t];
    __syncthreads();
    #pragma unroll
    for (int o = 1; o < 512; o <<= 1) {
        int v = (t >= o) ? hist[t - o] : 0;
        __syncthreads();
        hist[t] += v;
        __syncthreads();
    }
    int excl = hist[t] - c0;
    cur[t] = excl;
    int gr = c * 512 + t;
    if (gr < N_NODES) {
        rowbeg3[path * N_NODES + gr] = (int)(slabbase + excl);
        rowend3[path * N_NODES + gr] = (int)(slabbase + excl + c0);
    }
    __syncthreads();

    for (int i = t; i < n; i += 512) {
        uint2 e = src[i];
        int rl = (e.x >> 16) & 511;
        int pos = atomicAdd(&cur[rl], 1);
        sortpk[slabbase + pos] = (e.x & 0xffffu) |
                                 ((uint)f2bf(__uint_as_float(e.y)) << 16);
    }
}

// ---------------------------------------------------------------------------
// Gather SpMM + bias + PReLU. grid (12500, 3). One wave per row.
// lane = (slot<<3)|dq: 8 edge slots x 8 dim-octets (16B uint4 gathers).
// Unroll x4 -> 32 edges in flight. 4B packed edges. Output emb bf16.
// ---------------------------------------------------------------------------
__global__ __launch_bounds__(256) void spmm_gather(const uint*   __restrict__ sortpk,
                                                   const int*    __restrict__ rowbeg3,
                                                   const int*    __restrict__ rowend3,
                                                   const ushort* __restrict__ s_all,
                                                   const float*  __restrict__ bg,
                                                   const float*  __restrict__ alpha,
                                                   ushort* __restrict__ emb)
{
    const int path = blockIdx.y;
    const int wid = blockIdx.x * 4 + (threadIdx.x >> 6);
    const int lane = threadIdx.x & 63;
    const int dq = lane & 7;          // dim-octet: dims [dq*8, dq*8+8)
    const int slot = lane >> 3;       // 8 edge slots
    const int e0 = rowbeg3[path * N_NODES + wid];
    const int e1 = rowend3[path * N_NODES + wid];
    const ushort* s_p = s_all + (size_t)path * N_NODES * 64;

    float acc[8] = {};
    for (int e = e0; e < e1; e += 32) {
        int ea = e + slot, eb = ea + 8, ec = ea + 16, ed = ea + 24;
        uint pka = (ea < e1) ? sortpk[ea] : 0u;
        uint pkb = (eb < e1) ? sortpk[eb] : 0u;
        uint pkc = (ec < e1) ? sortpk[ec] : 0u;
        uint pkd = (ed < e1) ? sortpk[ed] : 0u;
        uint4 ga = *(const uint4*)&s_p[(size_t)(pka & 0xffffu) * 64 + dq * 8];
        uint4 gb = *(const uint4*)&s_p[(size_t)(pkb & 0xffffu) * 64 + dq * 8];
        uint4 gc = *(const uint4*)&s_p[(size_t)(pkc & 0xffffu) * 64 + dq * 8];
        uint4 gd = *(const uint4*)&s_p[(size_t)(pkd & 0xffffu) * 64 + dq * 8];
        float va = bfh(pka);
        float vb = bfh(pkb);
        float vc = bfh(pkc);
        float vd = bfh(pkd);
        acc[0] += va * bfl(ga.x); acc[1] += va * bfh(ga.x);
        acc[2] += va * bfl(ga.y); acc[3] += va * bfh(ga.y);
        acc[4] += va * bfl(ga.z); acc[5] += va * bfh(ga.z);
        acc[6] += va * bfl(ga.w); acc[7] += va * bfh(ga.w);
        acc[0] += vb * bfl(gb.x); acc[1] += vb * bfh(gb.x);
        acc[2] += vb * bfl(gb.y); acc[3] += vb * bfh(gb.y);
        acc[4] += vb * bfl(gb.z); acc[5] += vb * bfh(gb.z);
        acc[6] += vb * bfl(gb.w); acc[7] += vb * bfh(gb.w);
        acc[0] += vc * bfl(gc.x); acc[1] += vc * bfh(gc.x);
        acc[2] += vc * bfl(gc.y); acc[3] += vc * bfh(gc.y);
        acc[4] += vc * bfl(gc.z); acc[5] += vc * bfh(gc.z);
        acc[6] += vc * bfl(gc.w); acc[7] += vc * bfh(gc.w);
        acc[0] += vd * bfl(gd.x); acc[1] += vd * bfh(gd.x);
        acc[2] += vd * bfl(gd.y); acc[3] += vd * bfh(gd.y);
        acc[4] += vd * bfl(gd.z); acc[5] += vd * bfh(gd.z);
        acc[6] += vd * bfl(gd.w); acc[7] += vd * bfh(gd.w);
    }
    #pragma unroll
    for (int j = 0; j < 8; ++j) {
        acc[j] += __shfl_xor(acc[j], 8);
        acc[j] += __shfl_xor(acc[j], 16);
        acc[j] += __shfl_xor(acc[j], 32);
    }

    if (slot == 0) {   // lanes 0..7 hold dims [dq*8, dq*8+8)
        const float al = alpha[path];
        const float* bgp = bg + path * 64;
        float x[8];
        #pragma unroll
        for (int j = 0; j < 8; ++j) {
            float v = acc[j] + bgp[dq * 8 + j];
            x[j] = v > 0.f ? v : al * v;
        }
        uint4 wv;
        wv.x = cvtpk2(x[0], x[1]);
        wv.y = cvtpk2(x[2], x[3]);
        wv.z = cvtpk2(x[4], x[5]);
        wv.w = cvtpk2(x[6], x[7]);
        *(uint4*)&emb[((size_t)path * N_NODES + wid) * 64 + dq * 8] = wv;
    }
}

// ---------------------------------------------------------------------------
// Attention partial sums: sp[p] += column-sums of tanh(emb_p @ Wa^T + ba)
// ---------------------------------------------------------------------------
__global__ __launch_bounds__(256) void postproc(const ushort* __restrict__ emb,
                                                const float* __restrict__ Wa,
                                                const float* __restrict__ ba,
                                                float* __restrict__ sp)
{
    __shared__ float Ws[64][64];
    __shared__ float As[64][64];
    __shared__ float red[16][64];
    const int t  = threadIdx.x;
    const int tx = t & 15;
    const int ty = t >> 4;
    const int nb = (N_NODES + 63) >> 6;
    const int p  = blockIdx.x / nb;
    const int tb = blockIdx.x % nb;
    const int row0 = tb * 64;
    const ushort* embp = emb + (size_t)p * N_NODES * 64;

    #pragma unroll
    for (int rep = 0; rep < 4; ++rep) {
        int id = rep * 1024 + t * 4;
        int e  = id >> 6;
        int k4 = id & 63;
        float4 wv = *(const float4*)&Wa[id];
        Ws[k4+0][e] = wv.x; Ws[k4+1][e] = wv.y;
        Ws[k4+2][e] = wv.z; Ws[k4+3][e] = wv.w;
    }
    #pragma unroll
    for (int rep = 0; rep < 2; ++rep) {
        int idx = rep * 256 + t;      // 0..511
        int m  = idx >> 3;
        int d8 = idx & 7;
        int gr = row0 + m;
        int gr2 = gr < N_NODES ? gr : N_NODES - 1;
        uint4 xv = *(const uint4*)&embp[(size_t)gr2 * 64 + d8 * 8];
        As[d8*8+0][m] = bfl(xv.x); As[d8*8+1][m] = bfh(xv.x);
        As[d8*8+2][m] = bfl(xv.y); As[d8*8+3][m] = bfh(xv.y);
        As[d8*8+4][m] = bfl(xv.z); As[d8*8+5][m] = bfh(xv.z);
        As[d8*8+6][m] = bfl(xv.w); As[d8*8+7][m] = bfh(xv.w);
    }
    __syncthreads();

    float acc[4][4] = {};
    #pragma unroll 8
    for (int kk = 0; kk < 64; ++kk) {
        float4 a4 = *(const float4*)&As[kk][ty * 4];
        float4 b4 = *(const float4*)&Ws[kk][tx * 4];
        float av[4] = {a4.x, a4.y, a4.z, a4.w};
        float bv[4] = {b4.x, b4.y, b4.z, b4.w};
        #pragma unroll
        for (int i = 0; i < 4; ++i)
            #pragma unroll
            for (int j = 0; j < 4; ++j)
                acc[i][j] += av[i] * bv[j];
    }

    float colsum[4] = {0.f, 0.f, 0.f, 0.f};
    #pragma unroll
    for (int i = 0; i < 4; ++i) {
        int gr = row0 + ty * 4 + i;
        if (gr < N_NODES) {
            #pragma unroll
            for (int j = 0; j < 4; ++j)
                colsum[j] += tanhf(acc[i][j] + ba[tx * 4 + j]);
        }
    }
    #pragma unroll
    for (int j = 0; j < 4; ++j) red[ty][tx * 4 + j] = colsum[j];
    __syncthreads();
    if (t < 64) {
        float ssum = 0.f;
        #pragma unroll
        for (int g = 0; g < 16; ++g) ssum += red[g][t];
        unsafeAtomicAdd(&sp[p * 64 + t], ssum);
    }
}

// ---------------------------------------------------------------------------
__global__ void beta_kernel(const float* __restrict__ sp,
                            const float* __restrict__ att,
                            float* __restrict__ beta)
{
    int lane = threadIdx.x;   // 64 threads
    float w[PP];
    #pragma unroll
    for (int p = 0; p < PP; ++p) {
        float x = sp[p * 64 + lane] * (1.0f / (float)N_NODES) * att[lane];
        #pragma unroll
        for (int off = 32; off; off >>= 1) x += __shfl_down(x, off);
        w[p] = __shfl(x, 0);
    }
    if (lane == 0) {
        float mx = fmaxf(w[0], fmaxf(w[1], w[2]));
        float e0 = __expf(w[0] - mx);
        float e1 = __expf(w[1] - mx);
        float e2 = __expf(w[2] - mx);
        float s = e0 + e1 + e2;
        beta[0] = e0 / s; beta[1] = e1 / s; beta[2] = e2 / s;
    }
}

// ---------------------------------------------------------------------------
// z[n][d] = sum_p beta[p] * emb[p][n][d]   (emb bf16, out fp32)
// ---------------------------------------------------------------------------
__global__ __launch_bounds__(256) void combine(const ushort* __restrict__ emb,
                                               const float* __restrict__ beta,
                                               float* __restrict__ out)
{
    const float b0 = beta[0], b1 = beta[1], b2 = beta[2];
    const size_t tot = (size_t)N_NODES * 64;
    size_t i = ((size_t)blockIdx.x * 256 + threadIdx.x) * 8;
    if (i < tot) {
        uint4 e0 = *(const uint4*)&emb[i];
        uint4 e1 = *(const uint4*)&emb[tot + i];
        uint4 e2 = *(const uint4*)&emb[2 * tot + i];
        float o[8];
        o[0] = b0*bfl(e0.x) + b1*bfl(e1.x) + b2*bfl(e2.x);
        o[1] = b0*bfh(e0.x) + b1*bfh(e1.x) + b2*bfh(e2.x);
        o[2] = b0*bfl(e0.y) + b1*bfl(e1.y) + b2*bfl(e2.y);
        o[3] = b0*bfh(e0.y) + b1*bfh(e1.y) + b2*bfh(e2.y);
        o[4] = b0*bfl(e0.z) + b1*bfl(e1.z) + b2*bfl(e2.z);
        o[5] = b0*bfh(e0.z) + b1*bfh(e1.z) + b2*bfh(e2.z);
        o[6] = b0*bfl(e0.w) + b1*bfl(e1.w) + b2*bfl(e2.w);
        o[7] = b0*bfh(e0.w) + b1*bfh(e1.w) + b2*bfh(e2.w);
        *(float4*)&out[i]     = make_float4(o[0], o[1], o[2], o[3]);
        *(float4*)&out[i + 4] = make_float4(o[4], o[5], o[6], o[7]);
    }
}

// ---------------------------------------------------------------------------
extern "C" void kernel_launch(void* const* d_in, const int* in_sizes, int n_in,
                              void* d_out, int out_size, void* d_ws, size_t ws_size,
                              hipStream_t stream)
{
    const float* feats = (const float*)d_in[0];
    const int*   rows  = (const int*)  d_in[1];
    const int*   cols  = (const int*)  d_in[2];
    const float* vals  = (const float*)d_in[3];
    const float* W0    = (const float*)d_in[4];
    const float* b0    = (const float*)d_in[5];
    const float* Wg    = (const float*)d_in[6];
    const float* bg    = (const float*)d_in[7];
    const float* alpha = (const float*)d_in[8];
    const float* Wa    = (const float*)d_in[9];
    const float* ba    = (const float*)d_in[10];
    const float* att   = (const float*)d_in[11];
    float* out = (float*)d_out;

    const size_t ND = (size_t)N_NODES * 64;      // 3.2M elements
    char* base = (char*)d_ws;
    ushort* emb    = (ushort*)base;              base += 3 * ND * 2;        // 19.2 MB
    ushort* h_bf   = (ushort*)base;              base += ND * 2;            // 6.4 MB
    ushort* s_all  = (ushort*)base;              base += 3 * ND * 2;        // 19.2 MB
    ushort* W0h    = (ushort*)base;              base += 64 * 1024 * 2;
    ushort* Wgh    = (ushort*)base;              base += PP * 64 * 64 * 2;
    int*    pcur3  = (int*)base;                 base += PP * NPC * 4;
    float*  sp     = (float*)base;               base += 192 * 4;
    float*  beta   = (float*)base;               base += 64 * 4;
    int*    rowbeg3 = (int*)base;                base += PP * N_NODES * 4;  // 600 KB
    int*    rowend3 = (int*)base;                base += PP * N_NODES * 4;  // 600 KB
    base = (char*)(((size_t)base + 255) & ~(size_t)255);
    uint2*  coarsebuf = (uint2*)base;            base += (size_t)PP * NPC * CCAP * 8;  // 41.5 MB
    uint*   sortpk    = (uint*)base;             base += (size_t)PP * NPC * CCAP * 4;  // 20.8 MB

    // zero pcur3 + sp (contiguous)
    hipMemsetAsync(pcur3, 0, (PP * NPC + 192) * sizeof(int), stream);

    split_weights<<<(64 * 1024 + PP * 64 * 64 + 255) / 256, 256, 0, stream>>>(
        W0, Wg, W0h, Wgh);

    gemm1_mfma<<<782, 256, 0, stream>>>(feats, W0h, b0, h_bf);
    gemm_s<<<dim3(782, 3), 256, 0, stream>>>(h_bf, Wgh, s_all);

    part1<<<dim3(EE / 2560, 3), 256, 0, stream>>>(rows, cols, vals, pcur3, coarsebuf);
    sort2<<<dim3(NPC, 3), 512, 0, stream>>>(coarsebuf, pcur3, sortpk, rowbeg3, rowend3);
    spmm_gather<<<dim3(N_NODES / 4, 3), 256, 0, stream>>>(
        sortpk, rowbeg3, rowend3, s_all, bg, alpha, emb);

    postproc<<<3 * 782, 256, 0, stream>>>(emb, Wa, ba, sp);
    beta_kernel<<<1, 64, 0, stream>>>(sp, att, beta);
    combine<<<(int)((ND / 8 + 255) / 256), 256, 0, stream>>>(emb, beta, out);
}